// Round 2
// baseline (1179.269 us; speedup 1.0000x reference)
//
#include <hip/hip_runtime.h>

typedef short s16x8 __attribute__((ext_vector_type(8)));
typedef unsigned short u16;
typedef u16 u16x8 __attribute__((ext_vector_type(8)));
typedef u16 u16x4 __attribute__((ext_vector_type(4)));
typedef float f32x4 __attribute__((ext_vector_type(4)));

#define DEVINL __device__ __forceinline__

DEVINL u16 f2bf(float f) {
    unsigned u = __float_as_uint(f);
    u += 0x7FFFu + ((u >> 16) & 1u);
    return (u16)(u >> 16);
}
DEVINL float bf2f(u16 h) { return __uint_as_float((unsigned)h << 16); }

DEVINL void gl2lds16(const void* g, void* l) {
    __builtin_amdgcn_global_load_lds((const __attribute__((address_space(1))) void*)g,
                                     (__attribute__((address_space(3))) void*)l, 16, 0, 0);
}

DEVINL f32x4 mfma16(s16x8 a, s16x8 b, f32x4 c) {
    return __builtin_amdgcn_mfma_f32_16x16x32_bf16(a, b, c, 0, 0, 0);
}

#define SBAR()   __builtin_amdgcn_s_barrier()
#define SCHEDB() __builtin_amdgcn_sched_barrier(0)
#define WLGKM0() do { asm volatile("s_waitcnt lgkmcnt(0)"); __builtin_amdgcn_sched_barrier(0); } while (0)
#define WVM(n)   do { asm volatile("s_waitcnt vmcnt(" #n ")" ::: "memory"); __builtin_amdgcn_sched_barrier(0); } while (0)

// ---------------------------------------------------------------------------
// Transpose-cast: src (K,N) fp32 row-major -> dst (N,K) bf16 row-major
// ---------------------------------------------------------------------------
__global__ __launch_bounds__(256) void tcast(
    const float* __restrict__ src, u16* __restrict__ dst, const int K, const int N)
{
    __shared__ float tile[32][33];
    const long k0 = (long)blockIdx.x * 32;
    const long n0 = (long)blockIdx.y * 32;
    const int tid = threadIdx.x;
    const int r = tid >> 3, c4 = (tid & 7) * 4;
    float4 v = *(const float4*)&src[(k0 + r) * N + n0 + c4];
    tile[r][c4] = v.x; tile[r][c4 + 1] = v.y; tile[r][c4 + 2] = v.z; tile[r][c4 + 3] = v.w;
    __syncthreads();
    u16x4 ov;
    ov[0] = f2bf(tile[c4][r]);     ov[1] = f2bf(tile[c4 + 1][r]);
    ov[2] = f2bf(tile[c4 + 2][r]); ov[3] = f2bf(tile[c4 + 3][r]);
    *(u16x4*)&dst[(n0 + r) * K + k0 + c4] = ov;
}

// ---------------------------------------------------------------------------
// RMSNorm (C=2048) fp32 -> bf16
// ---------------------------------------------------------------------------
__global__ __launch_bounds__(256) void rmsnorm_cast(
    const float* __restrict__ x, const float* __restrict__ wn, u16* __restrict__ out)
{
    const int C = 2048;
    const long row = blockIdx.x;
    const int tid = threadIdx.x;
    const float4* xr = (const float4*)(x + row * C);
    float4 a = xr[tid * 2], b = xr[tid * 2 + 1];
    float ss = a.x*a.x + a.y*a.y + a.z*a.z + a.w*a.w
             + b.x*b.x + b.y*b.y + b.z*b.z + b.w*b.w;
#pragma unroll
    for (int m = 1; m < 64; m <<= 1) ss += __shfl_xor(ss, m);
    __shared__ float red[4];
    if ((tid & 63) == 0) red[tid >> 6] = ss;
    __syncthreads();
    float scale = rsqrtf((red[0] + red[1] + red[2] + red[3]) * (1.f / 2048.f) + 1e-6f);
    const float4* wr = (const float4*)wn;
    float4 wa = wr[tid * 2], wb = wr[tid * 2 + 1];
    u16x8 o;
    o[0] = f2bf(a.x * scale * wa.x); o[1] = f2bf(a.y * scale * wa.y);
    o[2] = f2bf(a.z * scale * wa.z); o[3] = f2bf(a.w * scale * wa.w);
    o[4] = f2bf(b.x * scale * wb.x); o[5] = f2bf(b.y * scale * wb.y);
    o[6] = f2bf(b.z * scale * wb.z); o[7] = f2bf(b.w * scale * wb.w);
    *(u16x8*)&out[row * C + tid * 8] = o;
}

// ---------------------------------------------------------------------------
// 8-phase GEMM (m201 template port). BM=256, BN=128, BK=64, 512 thr, 8 waves
// (2M x 4N), wave output 128x32. 2 K-tiles/iter, 8 phases, per-phase:
// {ds_reads | one half-tile stage -> SBAR -> lgkm(0) -> setprio MFMA -> SBAR}.
// Counted vmcnt(4) at phases 4 and 8 only. LDS 96 KiB.
// Stage slots (iter j): P1: buf1.B (kt 2j+1, j>=1) | P3: buf0.A-h0 (kt 2j+2)
// P4: buf0.A-h1 | P5: buf0.B | P7: buf1.A-h0 (kt 2j+3) | P8: buf1.A-h1
// MODE 0: outB = bf16(acc)   MODE 1: outF = resid + acc (fp32)
// ---------------------------------------------------------------------------
template <int MODE>
__global__ __launch_bounds__(512, 2) void gemm8p(
    const u16* __restrict__ A, const u16* __restrict__ Bt,
    const int N, const int K,
    float* __restrict__ outF, u16* __restrict__ outB,
    const float* __restrict__ resid)
{
    __shared__ u16 As[2][2][128 * 64];   // [buf][half] 64 KiB
    __shared__ u16 Bs[2][128 * 64];      // 32 KiB
    const int tid = threadIdx.x;
    const int lane = tid & 63;
    const int w = tid >> 6;
    const int wm = w >> 2, wn = w & 3;   // 2M x 4N
    const int quad = lane >> 4, l16 = lane & 15;
    const long m0 = (long)blockIdx.x * 256;
    const long n0 = (long)blockIdx.y * 128;

    const int idx0 = tid, idx1 = 512 + tid;
    const int r0 = idx0 >> 3, r1 = idx1 >> 3;
    const u16* gA0 = A + (m0 + r0) * K + ((idx0 & 7) ^ (r0 & 7)) * 8;
    const u16* gA1 = A + (m0 + r1) * K + ((idx1 & 7) ^ (r1 & 7)) * 8;
    const u16* gB0 = Bt + (n0 + r0) * K + ((idx0 & 7) ^ (r0 & 7)) * 8;
    const u16* gB1 = Bt + (n0 + r1) * K + ((idx1 & 7) ^ (r1 & 7)) * 8;
    const long hstep = (long)128 * K;

    auto stageA = [&](int buf, int h, int k) {
        gl2lds16(gA0 + h * hstep + k, (char*)&As[buf][h][0] + idx0 * 16);
        gl2lds16(gA1 + h * hstep + k, (char*)&As[buf][h][0] + idx1 * 16);
    };
    auto stageB = [&](int buf, int k) {
        gl2lds16(gB0 + k, (char*)&Bs[buf][0] + idx0 * 16);
        gl2lds16(gB1 + k, (char*)&Bs[buf][0] + idx1 * 16);
    };

    const int arow = l16;            // + mt*16, within half wm
    const int asw  = l16 & 7;
    const int brow = wn * 32 + l16;  // + nt*16

    f32x4 acc[8][2] = {};
    const int NT = K >> 6, NI = NT >> 1;

    // prologue: kt0 -> buf0, kt1 -> buf1
    stageA(0, 0, 0); stageA(0, 1, 0); stageB(0, 0);
    stageA(1, 0, 64); stageA(1, 1, 64); stageB(1, 64);
    WVM(6);                           // buf0 resident
    SBAR();

    for (int j = 0; j < NI; ++j) {
        const int k0 = j << 7;
        const bool pf = (j + 1 < NI);

#pragma unroll
        for (int half = 0; half < 2; ++half) {  // half=0: buf0/kt=2j, half=1: buf1/kt=2j+1
            const u16* as_ = &As[half][wm][0];
            const u16* bs_ = &Bs[half][0];
            s16x8 a0[4][2], a1[4][2], b0[2], b1[2];

            // ---- phase 1: A m0-3 (both ks) + B ks0 ----
#pragma unroll
            for (int mt = 0; mt < 4; ++mt)
#pragma unroll
                for (int ks = 0; ks < 2; ++ks)
                    a0[mt][ks] = *(const s16x8*)&as_[(mt * 16 + arow) * 64 +
                                                     ((ks * 4 + quad) ^ asw) * 8];
#pragma unroll
            for (int nt = 0; nt < 2; ++nt)
                b0[nt] = *(const s16x8*)&bs_[(brow + nt * 16) * 64 + (quad ^ asw) * 8];
            if (half == 0) { if (j >= 1) stageB(1, k0 + 64); }
            else           { if (pf)     stageB(0, k0 + 128); }
            SCHEDB(); SBAR(); WLGKM0();
            __builtin_amdgcn_s_setprio(1);
#pragma unroll
            for (int mt = 0; mt < 4; ++mt)
#pragma unroll
                for (int nt = 0; nt < 2; ++nt)
                    acc[mt][nt] = mfma16(a0[mt][0], b0[nt], acc[mt][nt]);
            __builtin_amdgcn_s_setprio(0);
            SCHEDB(); SBAR();

            // ---- phase 2: A m4-7 (both ks) ----
#pragma unroll
            for (int mt = 0; mt < 4; ++mt)
#pragma unroll
                for (int ks = 0; ks < 2; ++ks)
                    a1[mt][ks] = *(const s16x8*)&as_[((mt + 4) * 16 + arow) * 64 +
                                                     ((ks * 4 + quad) ^ asw) * 8];
            SCHEDB(); SBAR(); WLGKM0();
            __builtin_amdgcn_s_setprio(1);
#pragma unroll
            for (int mt = 0; mt < 4; ++mt)
#pragma unroll
                for (int nt = 0; nt < 2; ++nt)
                    acc[mt + 4][nt] = mfma16(a1[mt][0], b0[nt], acc[mt + 4][nt]);
            __builtin_amdgcn_s_setprio(0);
            SCHEDB(); SBAR();

            // ---- phase 3: B ks1 ----
#pragma unroll
            for (int nt = 0; nt < 2; ++nt)
                b1[nt] = *(const s16x8*)&bs_[(brow + nt * 16) * 64 + ((4 + quad) ^ asw) * 8];
            if (half == 0) { if (pf) stageA(0, 0, k0 + 128); }
            else           { if (pf) stageA(1, 0, k0 + 192); }
            SCHEDB(); SBAR(); WLGKM0();
            __builtin_amdgcn_s_setprio(1);
#pragma unroll
            for (int mt = 0; mt < 4; ++mt)
#pragma unroll
                for (int nt = 0; nt < 2; ++nt)
                    acc[mt][nt] = mfma16(a0[mt][1], b1[nt], acc[mt][nt]);
            __builtin_amdgcn_s_setprio(0);
            SCHEDB(); SBAR();

            // ---- phase 4: no reads ----
            if (half == 0) { if (pf) stageA(0, 1, k0 + 128); }
            else           { if (pf) stageA(1, 1, k0 + 192); }
            SCHEDB(); SBAR();
            __builtin_amdgcn_s_setprio(1);
#pragma unroll
            for (int mt = 0; mt < 4; ++mt)
#pragma unroll
                for (int nt = 0; nt < 2; ++nt)
                    acc[mt + 4][nt] = mfma16(a1[mt][1], b1[nt], acc[mt + 4][nt]);
            __builtin_amdgcn_s_setprio(0);
            if (half == 0) { if (pf) { WVM(4); } else { WVM(0); } }  // buf1 ready for P5
            else           { WVM(4); }                               // buf0 ready for next P1
            SCHEDB(); SBAR();
        }
    }

#pragma unroll
    for (int mt = 0; mt < 8; ++mt)
#pragma unroll
        for (int reg = 0; reg < 4; ++reg) {
            long row = m0 + wm * 128 + mt * 16 + quad * 4 + reg;
#pragma unroll
            for (int nt = 0; nt < 2; ++nt) {
                long col = n0 + wn * 32 + nt * 16 + l16;
                float v = acc[mt][nt][reg];
                if (MODE == 0) {
                    outB[row * N + col] = f2bf(v);
                } else {
                    outF[row * N + col] = resid[row * N + col] + v;
                }
            }
        }
}

// ---------------------------------------------------------------------------
// 8-phase fused FFN up-projection: same template with dual B operands.
// u = bf16( silu(A@B1t^T) * (A@B2t^T) ).  LDS 128 KiB.
// Stage slots: P1: buf1.B1 | P2: buf1.B2 | P3/P4: buf0.A h0/h1 | P5: buf0.B1
// P6: buf0.B2 | P7/P8: buf1.A h0/h1.
// ---------------------------------------------------------------------------
__global__ __launch_bounds__(512, 2) void gemm8p_ffn(
    const u16* __restrict__ A, const u16* __restrict__ B1t, const u16* __restrict__ B2t,
    const int N, const int K, u16* __restrict__ outB)
{
    __shared__ u16 As[2][2][128 * 64];
    __shared__ u16 B1s[2][128 * 64];
    __shared__ u16 B2s[2][128 * 64];
    const int tid = threadIdx.x;
    const int lane = tid & 63;
    const int w = tid >> 6;
    const int wm = w >> 2, wn = w & 3;
    const int quad = lane >> 4, l16 = lane & 15;
    const long m0 = (long)blockIdx.x * 256;
    const long n0 = (long)blockIdx.y * 128;

    const int idx0 = tid, idx1 = 512 + tid;
    const int r0 = idx0 >> 3, r1 = idx1 >> 3;
    const int sw0 = ((idx0 & 7) ^ (r0 & 7)) * 8, sw1 = ((idx1 & 7) ^ (r1 & 7)) * 8;
    const u16* gA0 = A + (m0 + r0) * K + sw0;
    const u16* gA1 = A + (m0 + r1) * K + sw1;
    const u16* gB10 = B1t + (n0 + r0) * K + sw0;
    const u16* gB11 = B1t + (n0 + r1) * K + sw1;
    const u16* gB20 = B2t + (n0 + r0) * K + sw0;
    const u16* gB21 = B2t + (n0 + r1) * K + sw1;
    const long hstep = (long)128 * K;

    auto stageA = [&](int buf, int h, int k) {
        gl2lds16(gA0 + h * hstep + k, (char*)&As[buf][h][0] + idx0 * 16);
        gl2lds16(gA1 + h * hstep + k, (char*)&As[buf][h][0] + idx1 * 16);
    };
    auto stageB1 = [&](int buf, int k) {
        gl2lds16(gB10 + k, (char*)&B1s[buf][0] + idx0 * 16);
        gl2lds16(gB11 + k, (char*)&B1s[buf][0] + idx1 * 16);
    };
    auto stageB2 = [&](int buf, int k) {
        gl2lds16(gB20 + k, (char*)&B2s[buf][0] + idx0 * 16);
        gl2lds16(gB21 + k, (char*)&B2s[buf][0] + idx1 * 16);
    };

    const int arow = l16;
    const int asw  = l16 & 7;
    const int brow = wn * 32 + l16;

    f32x4 acc1[8][2] = {};
    f32x4 acc2[8][2] = {};
    const int NT = K >> 6, NI = NT >> 1;

    stageA(0, 0, 0); stageA(0, 1, 0); stageB1(0, 0); stageB2(0, 0);
    stageA(1, 0, 64); stageA(1, 1, 64); stageB1(1, 64); stageB2(1, 64);
    WVM(8);
    SBAR();

    for (int j = 0; j < NI; ++j) {
        const int k0 = j << 7;
        const bool pf = (j + 1 < NI);

#pragma unroll
        for (int half = 0; half < 2; ++half) {
            const u16* as_ = &As[half][wm][0];
            const u16* c1_ = &B1s[half][0];
            const u16* c2_ = &B2s[half][0];
            s16x8 a0[4][2], a1[4][2], b10[2], b20[2], b11[2], b21[2];

            // ---- phase 1: A m0-3 both ks + B1/B2 ks0 (12 reads) ----
#pragma unroll
            for (int mt = 0; mt < 4; ++mt)
#pragma unroll
                for (int ks = 0; ks < 2; ++ks)
                    a0[mt][ks] = *(const s16x8*)&as_[(mt * 16 + arow) * 64 +
                                                     ((ks * 4 + quad) ^ asw) * 8];
#pragma unroll
            for (int nt = 0; nt < 2; ++nt) {
                b10[nt] = *(const s16x8*)&c1_[(brow + nt * 16) * 64 + (quad ^ asw) * 8];
                b20[nt] = *(const s16x8*)&c2_[(brow + nt * 16) * 64 + (quad ^ asw) * 8];
            }
            if (half == 0) { if (j >= 1) stageB1(1, k0 + 64); }
            else           { if (pf)     stageB1(0, k0 + 128); }
            SCHEDB(); SBAR(); WLGKM0();
            __builtin_amdgcn_s_setprio(1);
#pragma unroll
            for (int mt = 0; mt < 4; ++mt)
#pragma unroll
                for (int nt = 0; nt < 2; ++nt) {
                    acc1[mt][nt] = mfma16(a0[mt][0], b10[nt], acc1[mt][nt]);
                    acc2[mt][nt] = mfma16(a0[mt][0], b20[nt], acc2[mt][nt]);
                }
            __builtin_amdgcn_s_setprio(0);
            SCHEDB(); SBAR();

            // ---- phase 2: A m4-7 both ks ----
#pragma unroll
            for (int mt = 0; mt < 4; ++mt)
#pragma unroll
                for (int ks = 0; ks < 2; ++ks)
                    a1[mt][ks] = *(const s16x8*)&as_[((mt + 4) * 16 + arow) * 64 +
                                                     ((ks * 4 + quad) ^ asw) * 8];
            if (half == 0) { if (j >= 1) stageB2(1, k0 + 64); }
            else           { if (pf)     stageB2(0, k0 + 128); }
            SCHEDB(); SBAR(); WLGKM0();
            __builtin_amdgcn_s_setprio(1);
#pragma unroll
            for (int mt = 0; mt < 4; ++mt)
#pragma unroll
                for (int nt = 0; nt < 2; ++nt) {
                    acc1[mt + 4][nt] = mfma16(a1[mt][0], b10[nt], acc1[mt + 4][nt]);
                    acc2[mt + 4][nt] = mfma16(a1[mt][0], b20[nt], acc2[mt + 4][nt]);
                }
            __builtin_amdgcn_s_setprio(0);
            SCHEDB(); SBAR();

            // ---- phase 3: B1/B2 ks1 ----
#pragma unroll
            for (int nt = 0; nt < 2; ++nt) {
                b11[nt] = *(const s16x8*)&c1_[(brow + nt * 16) * 64 + ((4 + quad) ^ asw) * 8];
                b21[nt] = *(const s16x8*)&c2_[(brow + nt * 16) * 64 + ((4 + quad) ^ asw) * 8];
            }
            if (half == 0) { if (pf) stageA(0, 0, k0 + 128); }
            else           { if (pf) stageA(1, 0, k0 + 192); }
            SCHEDB(); SBAR(); WLGKM0();
            __builtin_amdgcn_s_setprio(1);
#pragma unroll
            for (int mt = 0; mt < 4; ++mt)
#pragma unroll
                for (int nt = 0; nt < 2; ++nt) {
                    acc1[mt][nt] = mfma16(a0[mt][1], b11[nt], acc1[mt][nt]);
                    acc2[mt][nt] = mfma16(a0[mt][1], b21[nt], acc2[mt][nt]);
                }
            __builtin_amdgcn_s_setprio(0);
            SCHEDB(); SBAR();

            // ---- phase 4: no reads ----
            if (half == 0) { if (pf) stageA(0, 1, k0 + 128); }
            else           { if (pf) stageA(1, 1, k0 + 192); }
            SCHEDB(); SBAR();
            __builtin_amdgcn_s_setprio(1);
#pragma unroll
            for (int mt = 0; mt < 4; ++mt)
#pragma unroll
                for (int nt = 0; nt < 2; ++nt) {
                    acc1[mt + 4][nt] = mfma16(a1[mt][1], b11[nt], acc1[mt + 4][nt]);
                    acc2[mt + 4][nt] = mfma16(a1[mt][1], b21[nt], acc2[mt + 4][nt]);
                }
            __builtin_amdgcn_s_setprio(0);
            if (half == 0) { if (pf) { WVM(4); } else { WVM(0); } }
            else           { WVM(4); }
            SCHEDB(); SBAR();
        }
    }

#pragma unroll
    for (int mt = 0; mt < 8; ++mt)
#pragma unroll
        for (int reg = 0; reg < 4; ++reg) {
            long row = m0 + wm * 128 + mt * 16 + quad * 4 + reg;
#pragma unroll
            for (int nt = 0; nt < 2; ++nt) {
                long col = n0 + wn * 32 + nt * 16 + l16;
                float g = acc1[mt][nt][reg];
                float s = g / (1.f + __expf(-g));
                outB[row * N + col] = f2bf(s * acc2[mt][nt][reg]);
            }
        }
}

// ---------------------------------------------------------------------------
// RoPE, vectorized: one block per (b,t) row; q scaled by 1/sqrt(D).
// qkv (B*T, 6144) bf16 -> qT/kT [bh][t][d]
// ---------------------------------------------------------------------------
__global__ __launch_bounds__(256) void rope_qk(
    const u16* __restrict__ qkv, u16* __restrict__ qT, u16* __restrict__ kT)
{
    const int row = blockIdx.x;
    const int t = row & 2047, b = row >> 11;
    const int tid = threadIdx.x;
    __shared__ u16 buf[4096];
    const u16* src = qkv + (long)row * 6144;
    u16x8 aa = *(const u16x8*)&src[tid * 8];
    u16x8 kk = *(const u16x8*)&src[2048 + tid * 8];
    *(u16x8*)&buf[tid * 8] = aa;
    *(u16x8*)&buf[2048 + tid * 8] = kk;
    __syncthreads();
    const int c = tid * 8;
    const int h = c >> 7, dh = c & 127;
    const bool first = dh < 64;
    const int pc = first ? (c + 64) : (c - 64);
    float cs[8], sn[8];
#pragma unroll
    for (int j = 0; j < 8; ++j) {
        float inv = __expf(-(float)((dh & 63) + j) * 0.14391156831212787f); // ln(1e4)/64
        float ang = (float)t * inv;
        cs[j] = cosf(ang); sn[j] = sinf(ang);
    }
    const long obase = ((long)(b * 16 + h) * 2048 + t) * 128 + dh;
#pragma unroll
    for (int part = 0; part < 2; ++part) {
        const int base = part * 2048;
        u16x8 mine = *(const u16x8*)&buf[base + c];
        u16x8 oth  = *(const u16x8*)&buf[base + pc];
        const float qs = part ? 1.f : 0.08838834764831845f;
        u16x8 o;
#pragma unroll
        for (int j = 0; j < 8; ++j) {
            float xv = bf2f(mine[j]), yv = bf2f(oth[j]);
            float ov = first ? (xv * cs[j] - yv * sn[j]) : (yv * sn[j] + xv * cs[j]);
            o[j] = f2bf(ov * qs);
        }
        u16* dst = part ? kT : qT;
        *(u16x8*)&dst[obase] = o;
    }
}

// ---------------------------------------------------------------------------
// v transpose: qkv v-part (b,t)(h,d) -> vT [bh][d][t].  LDS stride 65 (odd).
// ---------------------------------------------------------------------------
__global__ __launch_bounds__(256) void vtrans(
    const u16* __restrict__ qkv, u16* __restrict__ vT)
{
    const int bh = blockIdx.x;
    const int b = bh >> 4, h = bh & 15;
    const int t0 = blockIdx.y * 64, d0 = blockIdx.z * 64;
    __shared__ u16 tile[64 * 65];
    const int tid = threadIdx.x;
#pragma unroll
    for (int rr = 0; rr < 2; ++rr) {
        int idx = rr * 256 + tid;
        int r = idx >> 3, c = (idx & 7) * 8;
        u16x8 v = *(const u16x8*)&qkv[(long)(b * 2048 + t0 + r) * 6144 + 4096 + h * 128 + d0 + c];
#pragma unroll
        for (int j = 0; j < 8; ++j) tile[r * 65 + c + j] = v[j];
    }
    __syncthreads();
#pragma unroll
    for (int rr = 0; rr < 2; ++rr) {
        int idx = rr * 256 + tid;
        int dd = idx >> 3, cc = (idx & 7) * 8;
        u16x8 o;
#pragma unroll
        for (int j = 0; j < 8; ++j) o[j] = tile[(cc + j) * 65 + dd];
        *(u16x8*)&vT[((long)bh * 128 + d0 + dd) * 2048 + t0 + cc] = o;
    }
}

// ---------------------------------------------------------------------------
// Flash attention, causal. grid (32 qtiles reversed, 32 bh), 256 thr (4 waves).
// ---------------------------------------------------------------------------
__global__ __launch_bounds__(256, 2) void attn_kernel(
    const u16* __restrict__ qT, const u16* __restrict__ kT,
    const u16* __restrict__ vT, u16* __restrict__ outT)
{
    const int T = 2048, D = 128;
    const int qt = gridDim.x - 1 - blockIdx.x;   // heavy q-tiles dispatch first
    const int bh = blockIdx.y;
    const int tid = threadIdx.x, lane = tid & 63, w = tid >> 6;
    const int quad = lane >> 4, l16 = lane & 15;
    const int qrow = qt * 64 + w * 16;

    __shared__ u16 Ks[2][64 * 128];
    __shared__ u16 Vs[2][128 * 64];
    __shared__ u16 Ps[4][16 * 64];

    s16x8 aq[4];
    const u16* qb = qT + ((long)bh * T + qrow + l16) * D;
#pragma unroll
    for (int kk = 0; kk < 4; ++kk)
        aq[kk] = *(const s16x8*)&qb[kk * 32 + quad * 8];

    f32x4 o[8] = {};
    float mi[4] = {-INFINITY, -INFINITY, -INFINITY, -INFINITY};
    float li[4] = {0.f, 0.f, 0.f, 0.f};

    const u16* kg0 = kT + (long)bh * T * D;
    const u16* vg0 = vT + (long)bh * D * T;

    auto stage = [&](int kt, int b) {
        const int k0 = kt * 64;
#pragma unroll
        for (int rr = 0; rr < 4; ++rr) {
            int idx = rr * 256 + tid;
            int kr = idx >> 4, kj = idx & 15;
            gl2lds16(kg0 + (long)(k0 + kr) * D + ((kj ^ (kr & 15)) * 8),
                     (char*)Ks[b] + idx * 16);
            int vr = idx >> 3, vj = idx & 7;
            gl2lds16(vg0 + (long)vr * T + k0 + ((vj ^ (vr & 7)) * 8),
                     (char*)Vs[b] + idx * 16);
        }
    };

    stage(0, 0);

    for (int kt = 0; kt <= qt; ++kt) {
        __syncthreads();                 // buf[kt&1] ready (loads had 1 full iter)
        if (kt < qt) stage(kt + 1, (kt + 1) & 1);
        const u16* ks_ = Ks[kt & 1];
        const u16* vs_ = Vs[kt & 1];
        const int k0 = kt * 64;

        // S = Q K^T
        f32x4 sf[4] = {};
#pragma unroll
        for (int kk = 0; kk < 4; ++kk) {
#pragma unroll
            for (int nt = 0; nt < 4; ++nt) {
                s16x8 kb = *(const s16x8*)&ks_[(nt * 16 + l16) * 128 +
                                               ((kk * 4 + quad) ^ (l16 & 15)) * 8];
                sf[nt] = __builtin_amdgcn_mfma_f32_16x16x32_bf16(aq[kk], kb, sf[nt], 0, 0, 0);
            }
        }

        float S[4][4];
        if (kt == qt) {   // diagonal tile: causal mask
#pragma unroll
            for (int nt = 0; nt < 4; ++nt) {
                int col = k0 + nt * 16 + l16;
#pragma unroll
                for (int reg = 0; reg < 4; ++reg) {
                    int row = qrow + quad * 4 + reg;
                    S[nt][reg] = (col <= row) ? sf[nt][reg] : -INFINITY;
                }
            }
        } else {
#pragma unroll
            for (int nt = 0; nt < 4; ++nt)
#pragma unroll
                for (int reg = 0; reg < 4; ++reg)
                    S[nt][reg] = sf[nt][reg];
        }

        float rm[4];
#pragma unroll
        for (int reg = 0; reg < 4; ++reg)
            rm[reg] = fmaxf(fmaxf(S[0][reg], S[1][reg]), fmaxf(S[2][reg], S[3][reg]));
#pragma unroll
        for (int m = 1; m < 16; m <<= 1)
#pragma unroll
            for (int reg = 0; reg < 4; ++reg)
                rm[reg] = fmaxf(rm[reg], __shfl_xor(rm[reg], m));

        float alpha[4], rs[4];
#pragma unroll
        for (int reg = 0; reg < 4; ++reg) {
            float mn = fmaxf(mi[reg], rm[reg]);
            alpha[reg] = __expf(mi[reg] - mn);
            mi[reg] = mn;
            rs[reg] = 0.f;
        }
#pragma unroll
        for (int nt = 0; nt < 4; ++nt)
#pragma unroll
            for (int reg = 0; reg < 4; ++reg) {
                float p = __expf(S[nt][reg] - mi[reg]);
                S[nt][reg] = p;
                rs[reg] += p;
            }
#pragma unroll
        for (int m = 1; m < 16; m <<= 1)
#pragma unroll
            for (int reg = 0; reg < 4; ++reg)
                rs[reg] += __shfl_xor(rs[reg], m);
#pragma unroll
        for (int reg = 0; reg < 4; ++reg)
            li[reg] = li[reg] * alpha[reg] + rs[reg];
#pragma unroll
        for (int dt = 0; dt < 8; ++dt)
#pragma unroll
            for (int reg = 0; reg < 4; ++reg)
                o[dt][reg] *= alpha[reg];

        // P -> LDS, wave-private region (no barrier needed), XOR-swizzled
#pragma unroll
        for (int nt = 0; nt < 4; ++nt)
#pragma unroll
            for (int reg = 0; reg < 4; ++reg) {
                int prow = quad * 4 + reg;
                int pcol = nt * 16 + l16;
                Ps[w][prow * 64 + (((pcol >> 3) ^ (prow & 7)) * 8) + (pcol & 7)]
                    = f2bf(S[nt][reg]);
            }

        // O += P V   (Ps read: row l16, chunk ks*4+quad, swizzled)
#pragma unroll
        for (int ks = 0; ks < 2; ++ks) {
            s16x8 pa = *(const s16x8*)&Ps[w][l16 * 64 +
                                             ((ks * 4 + quad) ^ (l16 & 7)) * 8];
#pragma unroll
            for (int dt = 0; dt < 8; ++dt) {
                s16x8 vb = *(const s16x8*)&vs_[(dt * 16 + l16) * 64 +
                                               ((ks * 4 + quad) ^ (l16 & 7)) * 8];
                o[dt] = __builtin_amdgcn_mfma_f32_16x16x32_bf16(pa, vb, o[dt], 0, 0, 0);
            }
        }
    }

    const int b = bh >> 4, h = bh & 15;
#pragma unroll
    for (int reg = 0; reg < 4; ++reg) {
        float inv = 1.f / li[reg];
        int t = qrow + quad * 4 + reg;
        u16* orow = outT + ((long)(b * T + t)) * 2048 + h * 128;
#pragma unroll
        for (int dt = 0; dt < 8; ++dt)
            orow[dt * 16 + l16] = f2bf(o[dt][reg] * inv);
    }
}

// ---------------------------------------------------------------------------
// Workspace layout (188 MiB total, unions by live-range):
//   Z 24 MiB: wqkv_t -> w3_t | wproj 8 | w1_t 22 | w2_t 22
//   C 16 MiB: h -> attn_out -> h2 | D 48 MiB: qkv -> u | E 48 MiB: q/k/vT -> x2
// ---------------------------------------------------------------------------
extern "C" void kernel_launch(void* const* d_in, const int* in_sizes, int n_in,
                              void* d_out, int out_size, void* d_ws, size_t ws_size,
                              hipStream_t stream) {
    const float* x      = (const float*)d_in[0];
    const float* wn1    = (const float*)d_in[1];
    const float* w_qkv  = (const float*)d_in[2];
    const float* w_proj = (const float*)d_in[3];
    const float* wn2    = (const float*)d_in[4];
    const float* w1     = (const float*)d_in[5];
    const float* w2     = (const float*)d_in[6];
    const float* w3     = (const float*)d_in[7];
    float* out = (float*)d_out;

    char* p = (char*)d_ws;
    u16* Z       = (u16*)p; p += (size_t)6144 * 2048 * 2;
    u16* wproj_t = (u16*)p; p += (size_t)2048 * 2048 * 2;
    u16* w1_t    = (u16*)p; p += (size_t)5632 * 2048 * 2;
    u16* w2_t    = (u16*)p; p += (size_t)5632 * 2048 * 2;
    u16* C       = (u16*)p; p += (size_t)4096 * 2048 * 2;
    u16* D       = (u16*)p; p += (size_t)4096 * 6144 * 2;
    u16* E       = (u16*)p; p += (size_t)3 * 32 * 2048 * 128 * 2;

    u16* wqkv_t = Z;
    u16* w3_t   = Z;
    u16* qT = E;
    u16* kT = E + (size_t)32 * 2048 * 128;
    u16* vT = E + (size_t)2 * 32 * 2048 * 128;
    float* x2 = (float*)E;
    u16* uu = D;

    tcast<<<dim3(64, 192), 256, 0, stream>>>(w_qkv, wqkv_t, 2048, 6144);
    tcast<<<dim3(64, 64), 256, 0, stream>>>(w_proj, wproj_t, 2048, 2048);
    tcast<<<dim3(64, 176), 256, 0, stream>>>(w1, w1_t, 2048, 5632);
    tcast<<<dim3(64, 176), 256, 0, stream>>>(w2, w2_t, 2048, 5632);

    rmsnorm_cast<<<4096, 256, 0, stream>>>(x, wn1, C);
    gemm8p<0><<<dim3(16, 48), 512, 0, stream>>>(C, wqkv_t, 6144, 2048,
                                                nullptr, D, nullptr);
    rope_qk<<<4096, 256, 0, stream>>>(D, qT, kT);
    vtrans<<<dim3(32, 32, 2), 256, 0, stream>>>(D, vT);

    tcast<<<dim3(176, 64), 256, 0, stream>>>(w3, w3_t, 5632, 2048);

    attn_kernel<<<dim3(32, 32), 256, 0, stream>>>(qT, kT, vT, C);

    gemm8p<1><<<dim3(16, 16), 512, 0, stream>>>(C, wproj_t, 2048, 2048,
                                                x2, nullptr, x);
    rmsnorm_cast<<<4096, 256, 0, stream>>>(x2, wn2, C);
    gemm8p_ffn<<<dim3(16, 44), 512, 0, stream>>>(C, w1_t, w2_t, 5632, 2048, uu);
    gemm8p<1><<<dim3(16, 16), 512, 0, stream>>>(uu, w3_t, 2048, 5632,
                                                out, nullptr, x2);
}

// Round 3
// 917.295 us; speedup vs baseline: 1.2856x; 1.2856x over previous
//
#include <hip/hip_runtime.h>

typedef short s16x8 __attribute__((ext_vector_type(8)));
typedef unsigned short u16;
typedef u16 u16x8 __attribute__((ext_vector_type(8)));
typedef u16 u16x4 __attribute__((ext_vector_type(4)));
typedef float f32x4 __attribute__((ext_vector_type(4)));

#define DEVINL __device__ __forceinline__

DEVINL u16 f2bf(float f) {
    unsigned u = __float_as_uint(f);
    u += 0x7FFFu + ((u >> 16) & 1u);
    return (u16)(u >> 16);
}
DEVINL float bf2f(u16 h) { return __uint_as_float((unsigned)h << 16); }

DEVINL void gl2lds16(const void* g, void* l) {
    __builtin_amdgcn_global_load_lds((const __attribute__((address_space(1))) void*)g,
                                     (__attribute__((address_space(3))) void*)l, 16, 0, 0);
}

DEVINL f32x4 mfma16(s16x8 a, s16x8 b, f32x4 c) {
    return __builtin_amdgcn_mfma_f32_16x16x32_bf16(a, b, c, 0, 0, 0);
}

#define SBAR()   __builtin_amdgcn_s_barrier()
#define SCHEDB() __builtin_amdgcn_sched_barrier(0)
#define WLGKM0() do { asm volatile("s_waitcnt lgkmcnt(0)"); __builtin_amdgcn_sched_barrier(0); } while (0)
#define WVM(n)   do { asm volatile("s_waitcnt vmcnt(" #n ")" ::: "memory"); __builtin_amdgcn_sched_barrier(0); } while (0)
#define PRIO1()  __builtin_amdgcn_s_setprio(1)
#define PRIO0()  __builtin_amdgcn_s_setprio(0)

// ---------------------------------------------------------------------------
// Transpose-cast: src (K,N) fp32 row-major -> dst (N,K) bf16 row-major
// ---------------------------------------------------------------------------
__global__ __launch_bounds__(256) void tcast(
    const float* __restrict__ src, u16* __restrict__ dst, const int K, const int N)
{
    __shared__ float tile[32][33];
    const long k0 = (long)blockIdx.x * 32;
    const long n0 = (long)blockIdx.y * 32;
    const int tid = threadIdx.x;
    const int r = tid >> 3, c4 = (tid & 7) * 4;
    float4 v = *(const float4*)&src[(k0 + r) * N + n0 + c4];
    tile[r][c4] = v.x; tile[r][c4 + 1] = v.y; tile[r][c4 + 2] = v.z; tile[r][c4 + 3] = v.w;
    __syncthreads();
    u16x4 ov;
    ov[0] = f2bf(tile[c4][r]);     ov[1] = f2bf(tile[c4 + 1][r]);
    ov[2] = f2bf(tile[c4 + 2][r]); ov[3] = f2bf(tile[c4 + 3][r]);
    *(u16x4*)&dst[(n0 + r) * K + k0 + c4] = ov;
}

// ---------------------------------------------------------------------------
// RMSNorm (C=2048) fp32 -> bf16
// ---------------------------------------------------------------------------
__global__ __launch_bounds__(256) void rmsnorm_cast(
    const float* __restrict__ x, const float* __restrict__ wn, u16* __restrict__ out)
{
    const int C = 2048;
    const long row = blockIdx.x;
    const int tid = threadIdx.x;
    const float4* xr = (const float4*)(x + row * C);
    float4 a = xr[tid * 2], b = xr[tid * 2 + 1];
    float ss = a.x*a.x + a.y*a.y + a.z*a.z + a.w*a.w
             + b.x*b.x + b.y*b.y + b.z*b.z + b.w*b.w;
#pragma unroll
    for (int m = 1; m < 64; m <<= 1) ss += __shfl_xor(ss, m);
    __shared__ float red[4];
    if ((tid & 63) == 0) red[tid >> 6] = ss;
    __syncthreads();
    float scale = rsqrtf((red[0] + red[1] + red[2] + red[3]) * (1.f / 2048.f) + 1e-6f);
    const float4* wr = (const float4*)wn;
    float4 wa = wr[tid * 2], wb = wr[tid * 2 + 1];
    u16x8 o;
    o[0] = f2bf(a.x * scale * wa.x); o[1] = f2bf(a.y * scale * wa.y);
    o[2] = f2bf(a.z * scale * wa.z); o[3] = f2bf(a.w * scale * wa.w);
    o[4] = f2bf(b.x * scale * wb.x); o[5] = f2bf(b.y * scale * wb.y);
    o[6] = f2bf(b.z * scale * wb.z); o[7] = f2bf(b.w * scale * wb.w);
    *(u16x8*)&out[row * C + tid * 8] = o;
}

// ---------------------------------------------------------------------------
// 8-phase-style GEMM. BM=256, BN=128, BK=64, 512 thr, 8 waves (4M x 2N),
// wave tile 64x64 (acc 4x4 = 64 regs). 2 K-tiles/iter, 4 phases of 16 MFMA.
// Stages spread one region/phase; counted vmcnt(4) once per K-tile.
// LDS 96 KiB: A 2buf x 2half x [128][64], B 2buf x [128][64]. XOR swizzle.
// Region liveness: A(buf) read only in its 1st phase; B(buf) in both.
// MODE 0: outB = bf16(acc)   MODE 1: outF = resid + acc (fp32)
// ---------------------------------------------------------------------------
template <int MODE>
__global__ __launch_bounds__(512, 2) void g8p(
    const u16* __restrict__ A, const u16* __restrict__ Bt,
    const int N, const int K,
    float* __restrict__ outF, u16* __restrict__ outB,
    const float* __restrict__ resid)
{
    __shared__ u16 As[2][2][128 * 64];   // 64 KiB
    __shared__ u16 Bs[2][128 * 64];      // 32 KiB
    const int tid = threadIdx.x;
    const int lane = tid & 63;
    const int w = tid >> 6;
    const int wm = w >> 1, wn = w & 1;   // 4M x 2N
    const int quad = lane >> 4, l16 = lane & 15;
    const int asw = l16 & 7;
    const long m0 = (long)blockIdx.x * 256;
    const long n0 = (long)blockIdx.y * 128;

    const int idx0 = tid, idx1 = 512 + tid;
    const int r0 = idx0 >> 3, r1 = idx1 >> 3;
    const int sc0 = ((idx0 & 7) ^ (r0 & 7)) * 8;
    const int sc1 = ((idx1 & 7) ^ (r1 & 7)) * 8;
    const u16* gA0 = A + (m0 + r0) * K + sc0;
    const u16* gA1 = A + (m0 + r1) * K + sc1;
    const u16* gB0 = Bt + (n0 + r0) * K + sc0;
    const u16* gB1 = Bt + (n0 + r1) * K + sc1;
    const long hstep = (long)128 * K;

    auto stageA = [&](int buf, int h, int k) {
        gl2lds16(gA0 + h * hstep + k, (char*)&As[buf][h][0] + idx0 * 16);
        gl2lds16(gA1 + h * hstep + k, (char*)&As[buf][h][0] + idx1 * 16);
    };
    auto stageB = [&](int buf, int k) {
        gl2lds16(gB0 + k, (char*)&Bs[buf][0] + idx0 * 16);
        gl2lds16(gB1 + k, (char*)&Bs[buf][0] + idx1 * 16);
    };

    const u16* aReg[2] = { &As[0][wm >> 1][0], &As[1][wm >> 1][0] };
    const int arow = (wm & 1) * 64 + l16;   // + mt*16
    const int brow = wn * 64 + l16;         // + nt*16

    f32x4 acc[4][4] = {};
    const int NT = K >> 6, NI = NT >> 1;

    // prologue: buf0 full (A.h0,A.h1,B), buf1 A only -> 10 loads
    stageA(0, 0, 0); stageA(0, 1, 0); stageB(0, 0);
    stageA(1, 0, 64); stageA(1, 1, 64);
    WVM(4);                  // buf0 complete; buf1.A (4) in flight
    SBAR();

    for (int j = 0; j < NI; ++j) {
        const int k0 = j << 7;
        const bool pf = (j + 1 < NI);
        s16x8 a[4][2], b[2][2], bb[2][2];

        // ---- P1 (buf0): A all (8 reads) + B nt0-1 (4); stage buf1.B ----
#pragma unroll
        for (int mt = 0; mt < 4; ++mt)
#pragma unroll
            for (int ks = 0; ks < 2; ++ks)
                a[mt][ks] = *(const s16x8*)&aReg[0][(arow + mt * 16) * 64 +
                                                    ((ks * 4 + quad) ^ asw) * 8];
#pragma unroll
        for (int nt = 0; nt < 2; ++nt)
#pragma unroll
            for (int ks = 0; ks < 2; ++ks)
                b[nt][ks] = *(const s16x8*)&Bs[0][(brow + nt * 16) * 64 +
                                                  ((ks * 4 + quad) ^ asw) * 8];
        stageB(1, k0 + 64);
        SCHEDB(); SBAR(); WLGKM0();
        PRIO1();
#pragma unroll
        for (int mt = 0; mt < 4; ++mt)
#pragma unroll
            for (int nt = 0; nt < 2; ++nt)
#pragma unroll
                for (int ks = 0; ks < 2; ++ks)
                    acc[mt][nt] = mfma16(a[mt][ks], b[nt][ks], acc[mt][nt]);
        PRIO0();
        SCHEDB(); SBAR();

        // ---- P2 (buf0): B nt2-3 (4); stage buf0'.A h0+h1; WVM ----
#pragma unroll
        for (int nt = 0; nt < 2; ++nt)
#pragma unroll
            for (int ks = 0; ks < 2; ++ks)
                bb[nt][ks] = *(const s16x8*)&Bs[0][(brow + (nt + 2) * 16) * 64 +
                                                   ((ks * 4 + quad) ^ asw) * 8];
        if (pf) { stageA(0, 0, k0 + 128); stageA(0, 1, k0 + 128); }
        SCHEDB(); SBAR(); WLGKM0();
        PRIO1();
#pragma unroll
        for (int mt = 0; mt < 4; ++mt)
#pragma unroll
            for (int nt = 0; nt < 2; ++nt)
#pragma unroll
                for (int ks = 0; ks < 2; ++ks)
                    acc[mt][nt + 2] = mfma16(a[mt][ks], bb[nt][ks], acc[mt][nt + 2]);
        PRIO0();
        if (pf) { WVM(4); } else { WVM(0); }   // buf1 (A prev-P4 + B P1) complete
        SBAR();

        // ---- P3 (buf1): A all + B nt0-1; stage buf0'.B ----
#pragma unroll
        for (int mt = 0; mt < 4; ++mt)
#pragma unroll
            for (int ks = 0; ks < 2; ++ks)
                a[mt][ks] = *(const s16x8*)&aReg[1][(arow + mt * 16) * 64 +
                                                    ((ks * 4 + quad) ^ asw) * 8];
#pragma unroll
        for (int nt = 0; nt < 2; ++nt)
#pragma unroll
            for (int ks = 0; ks < 2; ++ks)
                b[nt][ks] = *(const s16x8*)&Bs[1][(brow + nt * 16) * 64 +
                                                  ((ks * 4 + quad) ^ asw) * 8];
        if (pf) stageB(0, k0 + 128);
        SCHEDB(); SBAR(); WLGKM0();
        PRIO1();
#pragma unroll
        for (int mt = 0; mt < 4; ++mt)
#pragma unroll
            for (int nt = 0; nt < 2; ++nt)
#pragma unroll
                for (int ks = 0; ks < 2; ++ks)
                    acc[mt][nt] = mfma16(a[mt][ks], b[nt][ks], acc[mt][nt]);
        PRIO0();
        SCHEDB(); SBAR();

        // ---- P4 (buf1): B nt2-3; stage buf1'.A h0+h1; WVM(4) ----
#pragma unroll
        for (int nt = 0; nt < 2; ++nt)
#pragma unroll
            for (int ks = 0; ks < 2; ++ks)
                bb[nt][ks] = *(const s16x8*)&Bs[1][(brow + (nt + 2) * 16) * 64 +
                                                   ((ks * 4 + quad) ^ asw) * 8];
        if (pf) { stageA(1, 0, k0 + 192); stageA(1, 1, k0 + 192); }
        SCHEDB(); SBAR(); WLGKM0();
        PRIO1();
#pragma unroll
        for (int mt = 0; mt < 4; ++mt)
#pragma unroll
            for (int nt = 0; nt < 2; ++nt)
#pragma unroll
                for (int ks = 0; ks < 2; ++ks)
                    acc[mt][nt + 2] = mfma16(a[mt][ks], bb[nt][ks], acc[mt][nt + 2]);
        PRIO0();
        if (pf) { WVM(4); }                     // buf0' complete
        SBAR();
    }

#pragma unroll
    for (int mt = 0; mt < 4; ++mt)
#pragma unroll
        for (int reg = 0; reg < 4; ++reg) {
            long row = m0 + wm * 64 + mt * 16 + quad * 4 + reg;
#pragma unroll
            for (int nt = 0; nt < 4; ++nt) {
                long col = n0 + wn * 64 + nt * 16 + l16;
                float v = acc[mt][nt][reg];
                if (MODE == 0) {
                    outB[row * N + col] = f2bf(v);
                } else {
                    outF[row * N + col] = resid[row * N + col] + v;
                }
            }
        }
}

// ---------------------------------------------------------------------------
// 8-phase fused FFN up-projection. BM=256, BN=128, dual B. LDS 128 KiB.
// Wave 64x64, dual acc (128 regs). 8 phases/iter, 16 MFMA each:
// P1:A*B1lo P2:A*B2lo P3:A*B1hi P4:A*B2hi (buf0); P5-8 same on buf1.
// Stage slots: P1:buf1.B2 | P2:buf0'.A | P4:buf0'.B1 | P5:buf0'.B2 |
// P6:buf1'.A | P8:buf1'.B1.  WVM(6) at P4/P8 (ledger-verified).
// u = bf16( silu(A@B1t^T) * (A@B2t^T) )
// ---------------------------------------------------------------------------
__global__ __launch_bounds__(512, 2) void g8p_ffn(
    const u16* __restrict__ A, const u16* __restrict__ B1t, const u16* __restrict__ B2t,
    const int N, const int K, u16* __restrict__ outB)
{
    __shared__ u16 As[2][2][128 * 64];   // 64 KiB
    __shared__ u16 B1s[2][128 * 64];     // 32 KiB
    __shared__ u16 B2s[2][128 * 64];     // 32 KiB
    const int tid = threadIdx.x;
    const int lane = tid & 63;
    const int w = tid >> 6;
    const int wm = w >> 1, wn = w & 1;
    const int quad = lane >> 4, l16 = lane & 15;
    const int asw = l16 & 7;
    const long m0 = (long)blockIdx.x * 256;
    const long n0 = (long)blockIdx.y * 128;

    const int idx0 = tid, idx1 = 512 + tid;
    const int r0 = idx0 >> 3, r1 = idx1 >> 3;
    const int sc0 = ((idx0 & 7) ^ (r0 & 7)) * 8;
    const int sc1 = ((idx1 & 7) ^ (r1 & 7)) * 8;
    const u16* gA0 = A + (m0 + r0) * K + sc0;
    const u16* gA1 = A + (m0 + r1) * K + sc1;
    const u16* gB10 = B1t + (n0 + r0) * K + sc0;
    const u16* gB11 = B1t + (n0 + r1) * K + sc1;
    const u16* gB20 = B2t + (n0 + r0) * K + sc0;
    const u16* gB21 = B2t + (n0 + r1) * K + sc1;
    const long hstep = (long)128 * K;

    auto stageA = [&](int buf, int h, int k) {
        gl2lds16(gA0 + h * hstep + k, (char*)&As[buf][h][0] + idx0 * 16);
        gl2lds16(gA1 + h * hstep + k, (char*)&As[buf][h][0] + idx1 * 16);
    };
    auto stageB1 = [&](int buf, int k) {
        gl2lds16(gB10 + k, (char*)&B1s[buf][0] + idx0 * 16);
        gl2lds16(gB11 + k, (char*)&B1s[buf][0] + idx1 * 16);
    };
    auto stageB2 = [&](int buf, int k) {
        gl2lds16(gB20 + k, (char*)&B2s[buf][0] + idx0 * 16);
        gl2lds16(gB21 + k, (char*)&B2s[buf][0] + idx1 * 16);
    };

    const u16* aReg[2] = { &As[0][wm >> 1][0], &As[1][wm >> 1][0] };
    const int arow = (wm & 1) * 64 + l16;
    const int brow = wn * 64 + l16;

    f32x4 acc1[4][4] = {};
    f32x4 acc2[4][4] = {};
    const int NT = K >> 6, NI = NT >> 1;

    // prologue: buf0 full (A,B1,B2 = 8), buf1 A+B1 (6) -> 14 loads
    stageA(0, 0, 0); stageA(0, 1, 0); stageB1(0, 0); stageB2(0, 0);
    stageA(1, 0, 64); stageA(1, 1, 64); stageB1(1, 64);
    WVM(6);                  // buf0 complete; buf1 A+B1 (6) in flight
    SBAR();

    for (int j = 0; j < NI; ++j) {
        const int k0 = j << 7;
        const bool pf = (j + 1 < NI);
        s16x8 a[4][2], b[2][2];

#pragma unroll
        for (int half = 0; half < 2; ++half) {
            const u16* ar = aReg[half];
            const u16* b1_ = &B1s[half][0];
            const u16* b2_ = &B2s[half][0];
            f32x4 (*ac1)[4] = acc1;
            f32x4 (*ac2)[4] = acc2;

            // ---- phase h.1: A all (8) + B1 nt0-1 (4) ----
#pragma unroll
            for (int mt = 0; mt < 4; ++mt)
#pragma unroll
                for (int ks = 0; ks < 2; ++ks)
                    a[mt][ks] = *(const s16x8*)&ar[(arow + mt * 16) * 64 +
                                                   ((ks * 4 + quad) ^ asw) * 8];
#pragma unroll
            for (int nt = 0; nt < 2; ++nt)
#pragma unroll
                for (int ks = 0; ks < 2; ++ks)
                    b[nt][ks] = *(const s16x8*)&b1_[(brow + nt * 16) * 64 +
                                                    ((ks * 4 + quad) ^ asw) * 8];
            if (half == 0) stageB2(1, k0 + 64);             // buf1.B2 (tile 2j+1)
            else if (pf)   stageB2(0, k0 + 128);            // buf0'.B2
            SCHEDB(); SBAR(); WLGKM0();
            PRIO1();
#pragma unroll
            for (int mt = 0; mt < 4; ++mt)
#pragma unroll
                for (int nt = 0; nt < 2; ++nt)
#pragma unroll
                    for (int ks = 0; ks < 2; ++ks)
                        ac1[mt][nt] = mfma16(a[mt][ks], b[nt][ks], ac1[mt][nt]);
            PRIO0();
            SCHEDB(); SBAR();

            // ---- phase h.2: B2 nt0-1 (4) ----
#pragma unroll
            for (int nt = 0; nt < 2; ++nt)
#pragma unroll
                for (int ks = 0; ks < 2; ++ks)
                    b[nt][ks] = *(const s16x8*)&b2_[(brow + nt * 16) * 64 +
                                                    ((ks * 4 + quad) ^ asw) * 8];
            if (half == 0) { if (pf) { stageA(0, 0, k0 + 128); stageA(0, 1, k0 + 128); } }
            else           { if (pf) { stageA(1, 0, k0 + 192); stageA(1, 1, k0 + 192); } }
            SCHEDB(); SBAR(); WLGKM0();
            PRIO1();
#pragma unroll
            for (int mt = 0; mt < 4; ++mt)
#pragma unroll
                for (int nt = 0; nt < 2; ++nt)
#pragma unroll
                    for (int ks = 0; ks < 2; ++ks)
                        ac2[mt][nt] = mfma16(a[mt][ks], b[nt][ks], ac2[mt][nt]);
            PRIO0();
            SCHEDB(); SBAR();

            // ---- phase h.3: B1 nt2-3 (4) ----
#pragma unroll
            for (int nt = 0; nt < 2; ++nt)
#pragma unroll
                for (int ks = 0; ks < 2; ++ks)
                    b[nt][ks] = *(const s16x8*)&b1_[(brow + (nt + 2) * 16) * 64 +
                                                    ((ks * 4 + quad) ^ asw) * 8];
            SCHEDB(); SBAR(); WLGKM0();
            PRIO1();
#pragma unroll
            for (int mt = 0; mt < 4; ++mt)
#pragma unroll
                for (int nt = 0; nt < 2; ++nt)
#pragma unroll
                    for (int ks = 0; ks < 2; ++ks)
                        ac1[mt][nt + 2] = mfma16(a[mt][ks], b[nt][ks], ac1[mt][nt + 2]);
            PRIO0();
            SCHEDB(); SBAR();

            // ---- phase h.4: B2 nt2-3 (4); stage; WVM(6) ----
#pragma unroll
            for (int nt = 0; nt < 2; ++nt)
#pragma unroll
                for (int ks = 0; ks < 2; ++ks)
                    b[nt][ks] = *(const s16x8*)&b2_[(brow + (nt + 2) * 16) * 64 +
                                                    ((ks * 4 + quad) ^ asw) * 8];
            if (half == 0) { if (pf) stageB1(0, k0 + 128); }   // buf0'.B1
            else           { if (pf) stageB1(1, k0 + 192); }   // buf1'.B1
            SCHEDB(); SBAR(); WLGKM0();
            PRIO1();
#pragma unroll
            for (int mt = 0; mt < 4; ++mt)
#pragma unroll
                for (int nt = 0; nt < 2; ++nt)
#pragma unroll
                    for (int ks = 0; ks < 2; ++ks)
                        ac2[mt][nt + 2] = mfma16(a[mt][ks], b[nt][ks], ac2[mt][nt + 2]);
            PRIO0();
            if (half == 0) { if (pf) { WVM(6); } else { WVM(0); } }  // buf1 complete
            else           { if (pf) { WVM(6); } }                   // buf0' complete
            SBAR();
        }
    }

#pragma unroll
    for (int mt = 0; mt < 4; ++mt)
#pragma unroll
        for (int reg = 0; reg < 4; ++reg) {
            long row = m0 + wm * 64 + mt * 16 + quad * 4 + reg;
#pragma unroll
            for (int nt = 0; nt < 4; ++nt) {
                long col = n0 + wn * 64 + nt * 16 + l16;
                float g = acc1[mt][nt][reg];
                float s = g / (1.f + __expf(-g));
                outB[row * N + col] = f2bf(s * acc2[mt][nt][reg]);
            }
        }
}

// ---------------------------------------------------------------------------
// RoPE, vectorized: one block per (b,t) row; q scaled by 1/sqrt(D).
// qkv (B*T, 6144) bf16 -> qT/kT [bh][t][d]
// ---------------------------------------------------------------------------
__global__ __launch_bounds__(256) void rope_qk(
    const u16* __restrict__ qkv, u16* __restrict__ qT, u16* __restrict__ kT)
{
    const int row = blockIdx.x;
    const int t = row & 2047, b = row >> 11;
    const int tid = threadIdx.x;
    __shared__ u16 buf[4096];
    const u16* src = qkv + (long)row * 6144;
    u16x8 aa = *(const u16x8*)&src[tid * 8];
    u16x8 kk = *(const u16x8*)&src[2048 + tid * 8];
    *(u16x8*)&buf[tid * 8] = aa;
    *(u16x8*)&buf[2048 + tid * 8] = kk;
    __syncthreads();
    const int c = tid * 8;
    const int h = c >> 7, dh = c & 127;
    const bool first = dh < 64;
    const int pc = first ? (c + 64) : (c - 64);
    float cs[8], sn[8];
#pragma unroll
    for (int j = 0; j < 8; ++j) {
        float inv = __expf(-(float)((dh & 63) + j) * 0.14391156831212787f); // ln(1e4)/64
        float ang = (float)t * inv;
        cs[j] = cosf(ang); sn[j] = sinf(ang);
    }
    const long obase = ((long)(b * 16 + h) * 2048 + t) * 128 + dh;
#pragma unroll
    for (int part = 0; part < 2; ++part) {
        const int base = part * 2048;
        u16x8 mine = *(const u16x8*)&buf[base + c];
        u16x8 oth  = *(const u16x8*)&buf[base + pc];
        const float qs = part ? 1.f : 0.08838834764831845f;
        u16x8 o;
#pragma unroll
        for (int j = 0; j < 8; ++j) {
            float xv = bf2f(mine[j]), yv = bf2f(oth[j]);
            float ov = first ? (xv * cs[j] - yv * sn[j]) : (yv * sn[j] + xv * cs[j]);
            o[j] = f2bf(ov * qs);
        }
        u16* dst = part ? kT : qT;
        *(u16x8*)&dst[obase] = o;
    }
}

// ---------------------------------------------------------------------------
// v transpose: qkv v-part (b,t)(h,d) -> vT [bh][d][t].  LDS stride 65 (odd).
// ---------------------------------------------------------------------------
__global__ __launch_bounds__(256) void vtrans(
    const u16* __restrict__ qkv, u16* __restrict__ vT)
{
    const int bh = blockIdx.x;
    const int b = bh >> 4, h = bh & 15;
    const int t0 = blockIdx.y * 64, d0 = blockIdx.z * 64;
    __shared__ u16 tile[64 * 65];
    const int tid = threadIdx.x;
#pragma unroll
    for (int rr = 0; rr < 2; ++rr) {
        int idx = rr * 256 + tid;
        int r = idx >> 3, c = (idx & 7) * 8;
        u16x8 v = *(const u16x8*)&qkv[(long)(b * 2048 + t0 + r) * 6144 + 4096 + h * 128 + d0 + c];
#pragma unroll
        for (int j = 0; j < 8; ++j) tile[r * 65 + c + j] = v[j];
    }
    __syncthreads();
#pragma unroll
    for (int rr = 0; rr < 2; ++rr) {
        int idx = rr * 256 + tid;
        int dd = idx >> 3, cc = (idx & 7) * 8;
        u16x8 o;
#pragma unroll
        for (int j = 0; j < 8; ++j) o[j] = tile[(cc + j) * 65 + dd];
        *(u16x8*)&vT[((long)bh * 128 + d0 + dd) * 2048 + t0 + cc] = o;
    }
}

// ---------------------------------------------------------------------------
// Flash attention, causal. grid (32 qtiles reversed, 32 bh), 256 thr (4 waves).
// ---------------------------------------------------------------------------
__global__ __launch_bounds__(256, 2) void attn_kernel(
    const u16* __restrict__ qT, const u16* __restrict__ kT,
    const u16* __restrict__ vT, u16* __restrict__ outT)
{
    const int T = 2048, D = 128;
    const int qt = gridDim.x - 1 - blockIdx.x;   // heavy q-tiles dispatch first
    const int bh = blockIdx.y;
    const int tid = threadIdx.x, lane = tid & 63, w = tid >> 6;
    const int quad = lane >> 4, l16 = lane & 15;
    const int qrow = qt * 64 + w * 16;

    __shared__ u16 Ks[2][64 * 128];
    __shared__ u16 Vs[2][128 * 64];
    __shared__ u16 Ps[4][16 * 64];

    s16x8 aq[4];
    const u16* qb = qT + ((long)bh * T + qrow + l16) * D;
#pragma unroll
    for (int kk = 0; kk < 4; ++kk)
        aq[kk] = *(const s16x8*)&qb[kk * 32 + quad * 8];

    f32x4 o[8] = {};
    float mi[4] = {-INFINITY, -INFINITY, -INFINITY, -INFINITY};
    float li[4] = {0.f, 0.f, 0.f, 0.f};

    const u16* kg0 = kT + (long)bh * T * D;
    const u16* vg0 = vT + (long)bh * D * T;

    auto stage = [&](int kt, int b) {
        const int k0 = kt * 64;
#pragma unroll
        for (int rr = 0; rr < 4; ++rr) {
            int idx = rr * 256 + tid;
            int kr = idx >> 4, kj = idx & 15;
            gl2lds16(kg0 + (long)(k0 + kr) * D + ((kj ^ (kr & 15)) * 8),
                     (char*)Ks[b] + idx * 16);
            int vr = idx >> 3, vj = idx & 7;
            gl2lds16(vg0 + (long)vr * T + k0 + ((vj ^ (vr & 7)) * 8),
                     (char*)Vs[b] + idx * 16);
        }
    };

    stage(0, 0);

    for (int kt = 0; kt <= qt; ++kt) {
        __syncthreads();                 // buf[kt&1] ready (loads had 1 full iter)
        if (kt < qt) stage(kt + 1, (kt + 1) & 1);
        const u16* ks_ = Ks[kt & 1];
        const u16* vs_ = Vs[kt & 1];
        const int k0 = kt * 64;

        // S = Q K^T
        f32x4 sf[4] = {};
#pragma unroll
        for (int kk = 0; kk < 4; ++kk) {
#pragma unroll
            for (int nt = 0; nt < 4; ++nt) {
                s16x8 kb = *(const s16x8*)&ks_[(nt * 16 + l16) * 128 +
                                               ((kk * 4 + quad) ^ (l16 & 15)) * 8];
                sf[nt] = __builtin_amdgcn_mfma_f32_16x16x32_bf16(aq[kk], kb, sf[nt], 0, 0, 0);
            }
        }

        float S[4][4];
        if (kt == qt) {   // diagonal tile: causal mask
#pragma unroll
            for (int nt = 0; nt < 4; ++nt) {
                int col = k0 + nt * 16 + l16;
#pragma unroll
                for (int reg = 0; reg < 4; ++reg) {
                    int row = qrow + quad * 4 + reg;
                    S[nt][reg] = (col <= row) ? sf[nt][reg] : -INFINITY;
                }
            }
        } else {
#pragma unroll
            for (int nt = 0; nt < 4; ++nt)
#pragma unroll
                for (int reg = 0; reg < 4; ++reg)
                    S[nt][reg] = sf[nt][reg];
        }

        float rm[4];
#pragma unroll
        for (int reg = 0; reg < 4; ++reg)
            rm[reg] = fmaxf(fmaxf(S[0][reg], S[1][reg]), fmaxf(S[2][reg], S[3][reg]));
#pragma unroll
        for (int m = 1; m < 16; m <<= 1)
#pragma unroll
            for (int reg = 0; reg < 4; ++reg)
                rm[reg] = fmaxf(rm[reg], __shfl_xor(rm[reg], m));

        float alpha[4], rs[4];
#pragma unroll
        for (int reg = 0; reg < 4; ++reg) {
            float mn = fmaxf(mi[reg], rm[reg]);
            alpha[reg] = __expf(mi[reg] - mn);
            mi[reg] = mn;
            rs[reg] = 0.f;
        }
#pragma unroll
        for (int nt = 0; nt < 4; ++nt)
#pragma unroll
            for (int reg = 0; reg < 4; ++reg) {
                float p = __expf(S[nt][reg] - mi[reg]);
                S[nt][reg] = p;
                rs[reg] += p;
            }
#pragma unroll
        for (int m = 1; m < 16; m <<= 1)
#pragma unroll
            for (int reg = 0; reg < 4; ++reg)
                rs[reg] += __shfl_xor(rs[reg], m);
#pragma unroll
        for (int reg = 0; reg < 4; ++reg)
            li[reg] = li[reg] * alpha[reg] + rs[reg];
#pragma unroll
        for (int dt = 0; dt < 8; ++dt)
#pragma unroll
            for (int reg = 0; reg < 4; ++reg)
                o[dt][reg] *= alpha[reg];

        // P -> LDS, wave-private region (no barrier needed), XOR-swizzled
#pragma unroll
        for (int nt = 0; nt < 4; ++nt)
#pragma unroll
            for (int reg = 0; reg < 4; ++reg) {
                int prow = quad * 4 + reg;
                int pcol = nt * 16 + l16;
                Ps[w][prow * 64 + (((pcol >> 3) ^ (prow & 7)) * 8) + (pcol & 7)]
                    = f2bf(S[nt][reg]);
            }

        // O += P V   (Ps read: row l16, chunk ks*4+quad, swizzled)
#pragma unroll
        for (int ks = 0; ks < 2; ++ks) {
            s16x8 pa = *(const s16x8*)&Ps[w][l16 * 64 +
                                             ((ks * 4 + quad) ^ (l16 & 7)) * 8];
#pragma unroll
            for (int dt = 0; dt < 8; ++dt) {
                s16x8 vb = *(const s16x8*)&vs_[(dt * 16 + l16) * 64 +
                                               ((ks * 4 + quad) ^ (l16 & 7)) * 8];
                o[dt] = __builtin_amdgcn_mfma_f32_16x16x32_bf16(pa, vb, o[dt], 0, 0, 0);
            }
        }
    }

    const int b = bh >> 4, h = bh & 15;
#pragma unroll
    for (int reg = 0; reg < 4; ++reg) {
        float inv = 1.f / li[reg];
        int t = qrow + quad * 4 + reg;
        u16* orow = outT + ((long)(b * T + t)) * 2048 + h * 128;
#pragma unroll
        for (int dt = 0; dt < 8; ++dt)
            orow[dt * 16 + l16] = f2bf(o[dt][reg] * inv);
    }
}

// ---------------------------------------------------------------------------
// Workspace layout (188 MiB total, unions by live-range):
//   Z 24 MiB: wqkv_t -> w3_t | wproj 8 | w1_t 22 | w2_t 22
//   C 16 MiB: h -> attn_out -> h2 | D 48 MiB: qkv -> u | E 48 MiB: q/k/vT -> x2
// ---------------------------------------------------------------------------
extern "C" void kernel_launch(void* const* d_in, const int* in_sizes, int n_in,
                              void* d_out, int out_size, void* d_ws, size_t ws_size,
                              hipStream_t stream) {
    const float* x      = (const float*)d_in[0];
    const float* wn1    = (const float*)d_in[1];
    const float* w_qkv  = (const float*)d_in[2];
    const float* w_proj = (const float*)d_in[3];
    const float* wn2    = (const float*)d_in[4];
    const float* w1     = (const float*)d_in[5];
    const float* w2     = (const float*)d_in[6];
    const float* w3     = (const float*)d_in[7];
    float* out = (float*)d_out;

    char* p = (char*)d_ws;
    u16* Z       = (u16*)p; p += (size_t)6144 * 2048 * 2;
    u16* wproj_t = (u16*)p; p += (size_t)2048 * 2048 * 2;
    u16* w1_t    = (u16*)p; p += (size_t)5632 * 2048 * 2;
    u16* w2_t    = (u16*)p; p += (size_t)5632 * 2048 * 2;
    u16* C       = (u16*)p; p += (size_t)4096 * 2048 * 2;
    u16* D       = (u16*)p; p += (size_t)4096 * 6144 * 2;
    u16* E       = (u16*)p; p += (size_t)3 * 32 * 2048 * 128 * 2;

    u16* wqkv_t = Z;
    u16* w3_t   = Z;
    u16* qT = E;
    u16* kT = E + (size_t)32 * 2048 * 128;
    u16* vT = E + (size_t)2 * 32 * 2048 * 128;
    float* x2 = (float*)E;
    u16* uu = D;

    tcast<<<dim3(64, 192), 256, 0, stream>>>(w_qkv, wqkv_t, 2048, 6144);
    tcast<<<dim3(64, 64), 256, 0, stream>>>(w_proj, wproj_t, 2048, 2048);
    tcast<<<dim3(64, 176), 256, 0, stream>>>(w1, w1_t, 2048, 5632);
    tcast<<<dim3(64, 176), 256, 0, stream>>>(w2, w2_t, 2048, 5632);

    rmsnorm_cast<<<4096, 256, 0, stream>>>(x, wn1, C);
    g8p<0><<<dim3(16, 48), 512, 0, stream>>>(C, wqkv_t, 6144, 2048,
                                             nullptr, D, nullptr);
    rope_qk<<<4096, 256, 0, stream>>>(D, qT, kT);
    vtrans<<<dim3(32, 32, 2), 256, 0, stream>>>(D, vT);

    tcast<<<dim3(176, 64), 256, 0, stream>>>(w3, w3_t, 5632, 2048);

    attn_kernel<<<dim3(32, 32), 256, 0, stream>>>(qT, kT, vT, C);

    g8p<1><<<dim3(16, 16), 512, 0, stream>>>(C, wproj_t, 2048, 2048,
                                             x2, nullptr, x);
    rmsnorm_cast<<<4096, 256, 0, stream>>>(x2, wn2, C);
    g8p_ffn<<<dim3(16, 44), 512, 0, stream>>>(C, w1_t, w2_t, 5632, 2048, uu);
    g8p<1><<<dim3(16, 16), 512, 0, stream>>>(uu, w3_t, 2048, 5632,
                                             out, nullptr, x2);
}

// Round 4
// 889.012 us; speedup vs baseline: 1.3265x; 1.0318x over previous
//
#include <hip/hip_runtime.h>

typedef short s16x8 __attribute__((ext_vector_type(8)));
typedef unsigned short u16;
typedef u16 u16x8 __attribute__((ext_vector_type(8)));
typedef u16 u16x4 __attribute__((ext_vector_type(4)));
typedef float f32x4 __attribute__((ext_vector_type(4)));

#define DEVINL __device__ __forceinline__

DEVINL u16 f2bf(float f) {
    unsigned u = __float_as_uint(f);
    u += 0x7FFFu + ((u >> 16) & 1u);
    return (u16)(u >> 16);
}
DEVINL float bf2f(u16 h) { return __uint_as_float((unsigned)h << 16); }

DEVINL void gl2lds16(const void* g, void* l) {
    __builtin_amdgcn_global_load_lds((const __attribute__((address_space(1))) void*)g,
                                     (__attribute__((address_space(3))) void*)l, 16, 0, 0);
}

// ---------------------------------------------------------------------------
// Transpose-cast: src (K,N) fp32 row-major -> dst (N,K) bf16 row-major
// ---------------------------------------------------------------------------
__global__ __launch_bounds__(256) void tcast(
    const float* __restrict__ src, u16* __restrict__ dst, const int K, const int N)
{
    __shared__ float tile[32][33];
    const long k0 = (long)blockIdx.x * 32;
    const long n0 = (long)blockIdx.y * 32;
    const int tid = threadIdx.x;
    const int r = tid >> 3, c4 = (tid & 7) * 4;
    float4 v = *(const float4*)&src[(k0 + r) * N + n0 + c4];
    tile[r][c4] = v.x; tile[r][c4 + 1] = v.y; tile[r][c4 + 2] = v.z; tile[r][c4 + 3] = v.w;
    __syncthreads();
    u16x4 ov;
    ov[0] = f2bf(tile[c4][r]);     ov[1] = f2bf(tile[c4 + 1][r]);
    ov[2] = f2bf(tile[c4 + 2][r]); ov[3] = f2bf(tile[c4 + 3][r]);
    *(u16x4*)&dst[(n0 + r) * K + k0 + c4] = ov;
}

// ---------------------------------------------------------------------------
// RMSNorm (C=2048) fp32 -> bf16
// ---------------------------------------------------------------------------
__global__ __launch_bounds__(256) void rmsnorm_cast(
    const float* __restrict__ x, const float* __restrict__ wn, u16* __restrict__ out)
{
    const int C = 2048;
    const long row = blockIdx.x;
    const int tid = threadIdx.x;
    const float4* xr = (const float4*)(x + row * C);
    float4 a = xr[tid * 2], b = xr[tid * 2 + 1];
    float ss = a.x*a.x + a.y*a.y + a.z*a.z + a.w*a.w
             + b.x*b.x + b.y*b.y + b.z*b.z + b.w*b.w;
#pragma unroll
    for (int m = 1; m < 64; m <<= 1) ss += __shfl_xor(ss, m);
    __shared__ float red[4];
    if ((tid & 63) == 0) red[tid >> 6] = ss;
    __syncthreads();
    float scale = rsqrtf((red[0] + red[1] + red[2] + red[3]) * (1.f / 2048.f) + 1e-6f);
    const float4* wr = (const float4*)wn;
    float4 wa = wr[tid * 2], wb = wr[tid * 2 + 1];
    u16x8 o;
    o[0] = f2bf(a.x * scale * wa.x); o[1] = f2bf(a.y * scale * wa.y);
    o[2] = f2bf(a.z * scale * wa.z); o[3] = f2bf(a.w * scale * wa.w);
    o[4] = f2bf(b.x * scale * wb.x); o[5] = f2bf(b.y * scale * wb.y);
    o[6] = f2bf(b.z * scale * wb.z); o[7] = f2bf(b.w * scale * wb.w);
    *(u16x8*)&out[row * C + tid * 8] = o;
}

// ---------------------------------------------------------------------------
// GEMM: A (M x K) bf16 row-major, Bt (N x K) bf16 row-major, 128x128 tile.
// LDS tiles XOR-swizzled: chunk j of row r stored at slot j^(r&7).
// MODE 0: outB = bf16(acc)   MODE 1: outF = resid + acc (fp32)
// ---------------------------------------------------------------------------
template <int MODE>
__global__ __launch_bounds__(256, 2) void gemm128(
    const u16* __restrict__ A, const u16* __restrict__ Bt,
    const int N, const int K,
    float* __restrict__ outF, u16* __restrict__ outB,
    const float* __restrict__ resid)
{
    __shared__ u16 As[128 * 64];
    __shared__ u16 Bs[128 * 64];
    const int tid = threadIdx.x;
    const int lane = tid & 63;
    const int w = tid >> 6;
    const int wm = w >> 1, wn = w & 1;
    const int quad = lane >> 4, l16 = lane & 15;
    const long m0 = (long)blockIdx.x * 128;
    const long n0 = (long)blockIdx.y * 128;

    const u16* ga[4]; const u16* gb[4]; char* la[4]; char* lb[4];
#pragma unroll
    for (int rr = 0; rr < 4; ++rr) {
        int idx = rr * 256 + tid;
        int r = idx >> 3, j = idx & 7;
        int c = (j ^ (r & 7)) * 8;          // XOR source-swizzle
        ga[rr] = A + (m0 + r) * K + c;
        gb[rr] = Bt + (n0 + r) * K + c;
        la[rr] = (char*)As + idx * 16;
        lb[rr] = (char*)Bs + idx * 16;
    }

    f32x4 acc[4][4] = {};

    for (int k0 = 0; k0 < K; k0 += 64) {
#pragma unroll
        for (int rr = 0; rr < 4; ++rr) {
            gl2lds16(ga[rr] + k0, la[rr]);
            gl2lds16(gb[rr] + k0, lb[rr]);
        }
        __syncthreads();
#pragma unroll
        for (int ks = 0; ks < 2; ++ks) {
            s16x8 af[4], bfv[4];
#pragma unroll
            for (int mt = 0; mt < 4; ++mt)
                af[mt] = *(const s16x8*)&As[(wm * 64 + mt * 16 + l16) * 64 +
                                            ((ks * 4 + quad) ^ (l16 & 7)) * 8];
#pragma unroll
            for (int nt = 0; nt < 4; ++nt)
                bfv[nt] = *(const s16x8*)&Bs[(wn * 64 + nt * 16 + l16) * 64 +
                                             ((ks * 4 + quad) ^ (l16 & 7)) * 8];
#pragma unroll
            for (int mt = 0; mt < 4; ++mt)
#pragma unroll
                for (int nt = 0; nt < 4; ++nt)
                    acc[mt][nt] = __builtin_amdgcn_mfma_f32_16x16x32_bf16(af[mt], bfv[nt], acc[mt][nt], 0, 0, 0);
        }
        __syncthreads();
    }

#pragma unroll
    for (int mt = 0; mt < 4; ++mt)
#pragma unroll
        for (int reg = 0; reg < 4; ++reg) {
            long row = m0 + wm * 64 + mt * 16 + quad * 4 + reg;
#pragma unroll
            for (int nt = 0; nt < 4; ++nt) {
                long col = n0 + wn * 64 + nt * 16 + l16;
                float v = acc[mt][nt][reg];
                if (MODE == 0) {
                    outB[row * N + col] = f2bf(v);
                } else {
                    outF[row * N + col] = resid[row * N + col] + v;
                }
            }
        }
}

// ---------------------------------------------------------------------------
// Fused FFN up-projection: u = bf16( silu(A@B1t^T) * (A@B2t^T) )
// ---------------------------------------------------------------------------
__global__ __launch_bounds__(256, 2) void gemm_ffn(
    const u16* __restrict__ A, const u16* __restrict__ B1t, const u16* __restrict__ B2t,
    const int N, const int K, u16* __restrict__ outB)
{
    __shared__ u16 As[128 * 64];
    __shared__ u16 B1s[128 * 64];
    __shared__ u16 B2s[128 * 64];
    const int tid = threadIdx.x;
    const int lane = tid & 63;
    const int w = tid >> 6;
    const int wm = w >> 1, wn = w & 1;
    const int quad = lane >> 4, l16 = lane & 15;
    const long m0 = (long)blockIdx.x * 128;
    const long n0 = (long)blockIdx.y * 128;

    const u16* ga[4]; const u16* gb1[4]; const u16* gb2[4];
    char* la[4]; char* lb1[4]; char* lb2[4];
#pragma unroll
    for (int rr = 0; rr < 4; ++rr) {
        int idx = rr * 256 + tid;
        int r = idx >> 3, j = idx & 7;
        int c = (j ^ (r & 7)) * 8;
        ga[rr]  = A + (m0 + r) * K + c;
        gb1[rr] = B1t + (n0 + r) * K + c;
        gb2[rr] = B2t + (n0 + r) * K + c;
        la[rr]  = (char*)As + idx * 16;
        lb1[rr] = (char*)B1s + idx * 16;
        lb2[rr] = (char*)B2s + idx * 16;
    }

    f32x4 acc1[4][4] = {};
    f32x4 acc2[4][4] = {};

    for (int k0 = 0; k0 < K; k0 += 64) {
#pragma unroll
        for (int rr = 0; rr < 4; ++rr) {
            gl2lds16(ga[rr] + k0, la[rr]);
            gl2lds16(gb1[rr] + k0, lb1[rr]);
            gl2lds16(gb2[rr] + k0, lb2[rr]);
        }
        __syncthreads();
#pragma unroll
        for (int ks = 0; ks < 2; ++ks) {
            s16x8 af[4], b1f[4], b2f[4];
#pragma unroll
            for (int mt = 0; mt < 4; ++mt)
                af[mt] = *(const s16x8*)&As[(wm * 64 + mt * 16 + l16) * 64 +
                                            ((ks * 4 + quad) ^ (l16 & 7)) * 8];
#pragma unroll
            for (int nt = 0; nt < 4; ++nt) {
                b1f[nt] = *(const s16x8*)&B1s[(wn * 64 + nt * 16 + l16) * 64 +
                                              ((ks * 4 + quad) ^ (l16 & 7)) * 8];
                b2f[nt] = *(const s16x8*)&B2s[(wn * 64 + nt * 16 + l16) * 64 +
                                              ((ks * 4 + quad) ^ (l16 & 7)) * 8];
            }
#pragma unroll
            for (int mt = 0; mt < 4; ++mt)
#pragma unroll
                for (int nt = 0; nt < 4; ++nt) {
                    acc1[mt][nt] = __builtin_amdgcn_mfma_f32_16x16x32_bf16(af[mt], b1f[nt], acc1[mt][nt], 0, 0, 0);
                    acc2[mt][nt] = __builtin_amdgcn_mfma_f32_16x16x32_bf16(af[mt], b2f[nt], acc2[mt][nt], 0, 0, 0);
                }
        }
        __syncthreads();
    }

#pragma unroll
    for (int mt = 0; mt < 4; ++mt)
#pragma unroll
        for (int reg = 0; reg < 4; ++reg) {
            long row = m0 + wm * 64 + mt * 16 + quad * 4 + reg;
#pragma unroll
            for (int nt = 0; nt < 4; ++nt) {
                long col = n0 + wn * 64 + nt * 16 + l16;
                float g = acc1[mt][nt][reg];
                float s = g / (1.f + __expf(-g));
                outB[row * N + col] = f2bf(s * acc2[mt][nt][reg]);
            }
        }
}

// ---------------------------------------------------------------------------
// RoPE, vectorized: one block per (b,t) row; q scaled by 1/sqrt(D).
// qkv (B*T, 6144) bf16 -> qT/kT [bh][t][d]
// ---------------------------------------------------------------------------
__global__ __launch_bounds__(256) void rope_qk(
    const u16* __restrict__ qkv, u16* __restrict__ qT, u16* __restrict__ kT)
{
    const int row = blockIdx.x;
    const int t = row & 2047, b = row >> 11;
    const int tid = threadIdx.x;
    __shared__ u16 buf[4096];
    const u16* src = qkv + (long)row * 6144;
    u16x8 aa = *(const u16x8*)&src[tid * 8];
    u16x8 kk = *(const u16x8*)&src[2048 + tid * 8];
    *(u16x8*)&buf[tid * 8] = aa;
    *(u16x8*)&buf[2048 + tid * 8] = kk;
    __syncthreads();
    const int c = tid * 8;
    const int h = c >> 7, dh = c & 127;
    const bool first = dh < 64;
    const int pc = first ? (c + 64) : (c - 64);
    float cs[8], sn[8];
#pragma unroll
    for (int j = 0; j < 8; ++j) {
        float inv = __expf(-(float)((dh & 63) + j) * 0.14391156831212787f); // ln(1e4)/64
        float ang = (float)t * inv;
        cs[j] = cosf(ang); sn[j] = sinf(ang);
    }
    const long obase = ((long)(b * 16 + h) * 2048 + t) * 128 + dh;
#pragma unroll
    for (int part = 0; part < 2; ++part) {
        const int base = part * 2048;
        u16x8 mine = *(const u16x8*)&buf[base + c];
        u16x8 oth  = *(const u16x8*)&buf[base + pc];
        const float qs = part ? 1.f : 0.08838834764831845f;
        u16x8 o;
#pragma unroll
        for (int j = 0; j < 8; ++j) {
            float xv = bf2f(mine[j]), yv = bf2f(oth[j]);
            float ov = first ? (xv * cs[j] - yv * sn[j]) : (yv * sn[j] + xv * cs[j]);
            o[j] = f2bf(ov * qs);
        }
        u16* dst = part ? kT : qT;
        *(u16x8*)&dst[obase] = o;
    }
}

// ---------------------------------------------------------------------------
// v transpose: qkv v-part (b,t)(h,d) -> vT [bh][d][t].  LDS stride 65 (odd).
// ---------------------------------------------------------------------------
__global__ __launch_bounds__(256) void vtrans(
    const u16* __restrict__ qkv, u16* __restrict__ vT)
{
    const int bh = blockIdx.x;
    const int b = bh >> 4, h = bh & 15;
    const int t0 = blockIdx.y * 64, d0 = blockIdx.z * 64;
    __shared__ u16 tile[64 * 65];
    const int tid = threadIdx.x;
#pragma unroll
    for (int rr = 0; rr < 2; ++rr) {
        int idx = rr * 256 + tid;
        int r = idx >> 3, c = (idx & 7) * 8;
        u16x8 v = *(const u16x8*)&qkv[(long)(b * 2048 + t0 + r) * 6144 + 4096 + h * 128 + d0 + c];
#pragma unroll
        for (int j = 0; j < 8; ++j) tile[r * 65 + c + j] = v[j];
    }
    __syncthreads();
#pragma unroll
    for (int rr = 0; rr < 2; ++rr) {
        int idx = rr * 256 + tid;
        int dd = idx >> 3, cc = (idx & 7) * 8;
        u16x8 o;
#pragma unroll
        for (int j = 0; j < 8; ++j) o[j] = tile[(cc + j) * 65 + dd];
        *(u16x8*)&vT[((long)bh * 128 + d0 + dd) * 2048 + t0 + cc] = o;
    }
}

// ---------------------------------------------------------------------------
// Flash attention, causal. 4 waves, 32 q-rows per wave (QBLK=128/block).
// grid (16 qtiles reversed, 32 bh), 256 thr. K/V fragments shared across the
// two row-tiles -> 64 MFMA per 32 ds_read_b128 (was 32:32). Double-buffered
// K/V, XOR-swizzled LDS, q pre-scaled by 1/sqrt(D). T13 defer-max: skip
// o/li rescale while per-tile max growth <= 8.
// LDS: Ks 32K + Vs 32K + Ps 16K = 80 KiB -> 2 blocks/CU.
// ---------------------------------------------------------------------------
__global__ __launch_bounds__(256, 2) void attn_kernel(
    const u16* __restrict__ qT, const u16* __restrict__ kT,
    const u16* __restrict__ vT, u16* __restrict__ outT)
{
    const int T = 2048, D = 128;
    const int qt = gridDim.x - 1 - blockIdx.x;   // heavy q-tiles dispatch first
    const int bh = blockIdx.y;
    const int tid = threadIdx.x, lane = tid & 63, w = tid >> 6;
    const int quad = lane >> 4, l16 = lane & 15;
    const int qrow = qt * 128 + w * 32;          // wave owns rows [qrow, qrow+32)

    __shared__ u16 Ks[2][64 * 128];
    __shared__ u16 Vs[2][128 * 64];
    __shared__ u16 Ps[4][32 * 64];

    s16x8 aq[2][4];
#pragma unroll
    for (int rt = 0; rt < 2; ++rt) {
        const u16* qb = qT + ((long)bh * T + qrow + rt * 16 + l16) * D;
#pragma unroll
        for (int kk = 0; kk < 4; ++kk)
            aq[rt][kk] = *(const s16x8*)&qb[kk * 32 + quad * 8];
    }

    f32x4 o[2][8] = {};
    float mi[2][4], li[2][4];
#pragma unroll
    for (int rt = 0; rt < 2; ++rt)
#pragma unroll
        for (int r = 0; r < 4; ++r) { mi[rt][r] = -INFINITY; li[rt][r] = 0.f; }

    const u16* kg0 = kT + (long)bh * T * D;
    const u16* vg0 = vT + (long)bh * D * T;

    auto stage = [&](int kt, int b) {
        const int k0 = kt * 64;
#pragma unroll
        for (int rr = 0; rr < 4; ++rr) {
            int idx = rr * 256 + tid;
            int kr = idx >> 4, kj = idx & 15;
            gl2lds16(kg0 + (long)(k0 + kr) * D + ((kj ^ (kr & 15)) * 8),
                     (char*)Ks[b] + idx * 16);
            int vr = idx >> 3, vj = idx & 7;
            gl2lds16(vg0 + (long)vr * T + k0 + ((vj ^ (vr & 7)) * 8),
                     (char*)Vs[b] + idx * 16);
        }
    };

    const int nkt = 2 * qt + 2;
    stage(0, 0);

    for (int kt = 0; kt < nkt; ++kt) {
        __syncthreads();                 // buf[kt&1] ready (loads had 1 full iter)
        if (kt + 1 < nkt) stage(kt + 1, (kt + 1) & 1);
        const u16* ks_ = Ks[kt & 1];
        const u16* vs_ = Vs[kt & 1];
        const int k0 = kt * 64;

        // S = Q K^T, K fragments shared across both row-tiles
        f32x4 sf[2][4] = {};
#pragma unroll
        for (int kk = 0; kk < 4; ++kk) {
#pragma unroll
            for (int nt = 0; nt < 4; ++nt) {
                s16x8 kb = *(const s16x8*)&ks_[(nt * 16 + l16) * 128 +
                                               ((kk * 4 + quad) ^ (l16 & 15)) * 8];
                sf[0][nt] = __builtin_amdgcn_mfma_f32_16x16x32_bf16(aq[0][kk], kb, sf[0][nt], 0, 0, 0);
                sf[1][nt] = __builtin_amdgcn_mfma_f32_16x16x32_bf16(aq[1][kk], kb, sf[1][nt], 0, 0, 0);
            }
        }

        float S[2][4][4];
        if (kt >= 2 * qt) {   // diagonal region: causal mask
#pragma unroll
            for (int rt = 0; rt < 2; ++rt)
#pragma unroll
                for (int nt = 0; nt < 4; ++nt) {
                    int col = k0 + nt * 16 + l16;
#pragma unroll
                    for (int reg = 0; reg < 4; ++reg) {
                        int row = qrow + rt * 16 + quad * 4 + reg;
                        S[rt][nt][reg] = (col <= row) ? sf[rt][nt][reg] : -INFINITY;
                    }
                }
        } else {
#pragma unroll
            for (int rt = 0; rt < 2; ++rt)
#pragma unroll
                for (int nt = 0; nt < 4; ++nt)
#pragma unroll
                    for (int reg = 0; reg < 4; ++reg)
                        S[rt][nt][reg] = sf[rt][nt][reg];
        }

        // row max over nt (in-thread) then 16-lane shuffle groups
        float rm[2][4];
#pragma unroll
        for (int rt = 0; rt < 2; ++rt)
#pragma unroll
            for (int reg = 0; reg < 4; ++reg)
                rm[rt][reg] = fmaxf(fmaxf(S[rt][0][reg], S[rt][1][reg]),
                                    fmaxf(S[rt][2][reg], S[rt][3][reg]));
#pragma unroll
        for (int m = 1; m < 16; m <<= 1)
#pragma unroll
            for (int rt = 0; rt < 2; ++rt)
#pragma unroll
                for (int reg = 0; reg < 4; ++reg)
                    rm[rt][reg] = fmaxf(rm[rt][reg], __shfl_xor(rm[rt][reg], m));

        // T13 defer-max: only rescale when max grew by > 8
        int cond = 1;
#pragma unroll
        for (int rt = 0; rt < 2; ++rt)
#pragma unroll
            for (int reg = 0; reg < 4; ++reg)
                cond &= (rm[rt][reg] - mi[rt][reg] <= 8.f) ? 1 : 0;
        if (!__all(cond)) {
            float alpha[2][4];
#pragma unroll
            for (int rt = 0; rt < 2; ++rt)
#pragma unroll
                for (int reg = 0; reg < 4; ++reg) {
                    float mn = fmaxf(mi[rt][reg], rm[rt][reg]);
                    float al = __expf(mi[rt][reg] - mn);
                    mi[rt][reg] = mn;
                    li[rt][reg] *= al;
                    alpha[rt][reg] = al;
                }
#pragma unroll
            for (int rt = 0; rt < 2; ++rt)
#pragma unroll
                for (int dt = 0; dt < 8; ++dt)
#pragma unroll
                    for (int reg = 0; reg < 4; ++reg)
                        o[rt][dt][reg] *= alpha[rt][reg];
        }

        float rs[2][4] = {};
#pragma unroll
        for (int rt = 0; rt < 2; ++rt)
#pragma unroll
            for (int nt = 0; nt < 4; ++nt)
#pragma unroll
                for (int reg = 0; reg < 4; ++reg) {
                    float p = __expf(S[rt][nt][reg] - mi[rt][reg]);
                    S[rt][nt][reg] = p;
                    rs[rt][reg] += p;
                }
#pragma unroll
        for (int m = 1; m < 16; m <<= 1)
#pragma unroll
            for (int rt = 0; rt < 2; ++rt)
#pragma unroll
                for (int reg = 0; reg < 4; ++reg)
                    rs[rt][reg] += __shfl_xor(rs[rt][reg], m);
#pragma unroll
        for (int rt = 0; rt < 2; ++rt)
#pragma unroll
            for (int reg = 0; reg < 4; ++reg)
                li[rt][reg] += rs[rt][reg];

        // P -> LDS, wave-private region (no barrier needed), XOR-swizzled
#pragma unroll
        for (int rt = 0; rt < 2; ++rt)
#pragma unroll
            for (int nt = 0; nt < 4; ++nt)
#pragma unroll
                for (int reg = 0; reg < 4; ++reg) {
                    int prow = rt * 16 + quad * 4 + reg;
                    int pcol = nt * 16 + l16;
                    Ps[w][prow * 64 + (((pcol >> 3) ^ (prow & 7)) * 8) + (pcol & 7)]
                        = f2bf(S[rt][nt][reg]);
                }

        // O += P V  (V fragments shared across both row-tiles)
#pragma unroll
        for (int ks = 0; ks < 2; ++ks) {
            s16x8 pa0 = *(const s16x8*)&Ps[w][l16 * 64 +
                                              ((ks * 4 + quad) ^ (l16 & 7)) * 8];
            s16x8 pa1 = *(const s16x8*)&Ps[w][(16 + l16) * 64 +
                                              ((ks * 4 + quad) ^ (l16 & 7)) * 8];
#pragma unroll
            for (int dt = 0; dt < 8; ++dt) {
                s16x8 vb = *(const s16x8*)&vs_[(dt * 16 + l16) * 64 +
                                               ((ks * 4 + quad) ^ (l16 & 7)) * 8];
                o[0][dt] = __builtin_amdgcn_mfma_f32_16x16x32_bf16(pa0, vb, o[0][dt], 0, 0, 0);
                o[1][dt] = __builtin_amdgcn_mfma_f32_16x16x32_bf16(pa1, vb, o[1][dt], 0, 0, 0);
            }
        }
    }

    const int b = bh >> 4, h = bh & 15;
#pragma unroll
    for (int rt = 0; rt < 2; ++rt)
#pragma unroll
        for (int reg = 0; reg < 4; ++reg) {
            float inv = 1.f / li[rt][reg];
            int t = qrow + rt * 16 + quad * 4 + reg;
            u16* orow = outT + ((long)(b * T + t)) * 2048 + h * 128;
#pragma unroll
            for (int dt = 0; dt < 8; ++dt)
                orow[dt * 16 + l16] = f2bf(o[rt][dt][reg] * inv);
        }
}

// ---------------------------------------------------------------------------
// Workspace layout (188 MiB total, unions by live-range):
//   Z 24 MiB: wqkv_t -> w3_t | wproj 8 | w1_t 22 | w2_t 22
//   C 16 MiB: h -> attn_out -> h2 | D 48 MiB: qkv -> u | E 48 MiB: q/k/vT -> x2
// ---------------------------------------------------------------------------
extern "C" void kernel_launch(void* const* d_in, const int* in_sizes, int n_in,
                              void* d_out, int out_size, void* d_ws, size_t ws_size,
                              hipStream_t stream) {
    const float* x      = (const float*)d_in[0];
    const float* wn1    = (const float*)d_in[1];
    const float* w_qkv  = (const float*)d_in[2];
    const float* w_proj = (const float*)d_in[3];
    const float* wn2    = (const float*)d_in[4];
    const float* w1     = (const float*)d_in[5];
    const float* w2     = (const float*)d_in[6];
    const float* w3     = (const float*)d_in[7];
    float* out = (float*)d_out;

    char* p = (char*)d_ws;
    u16* Z       = (u16*)p; p += (size_t)6144 * 2048 * 2;
    u16* wproj_t = (u16*)p; p += (size_t)2048 * 2048 * 2;
    u16* w1_t    = (u16*)p; p += (size_t)5632 * 2048 * 2;
    u16* w2_t    = (u16*)p; p += (size_t)5632 * 2048 * 2;
    u16* C       = (u16*)p; p += (size_t)4096 * 2048 * 2;
    u16* D       = (u16*)p; p += (size_t)4096 * 6144 * 2;
    u16* E       = (u16*)p; p += (size_t)3 * 32 * 2048 * 128 * 2;

    u16* wqkv_t = Z;
    u16* w3_t   = Z;
    u16* qT = E;
    u16* kT = E + (size_t)32 * 2048 * 128;
    u16* vT = E + (size_t)2 * 32 * 2048 * 128;
    float* x2 = (float*)E;
    u16* uu = D;

    tcast<<<dim3(64, 192), 256, 0, stream>>>(w_qkv, wqkv_t, 2048, 6144);
    tcast<<<dim3(64, 64), 256, 0, stream>>>(w_proj, wproj_t, 2048, 2048);
    tcast<<<dim3(64, 176), 256, 0, stream>>>(w1, w1_t, 2048, 5632);
    tcast<<<dim3(64, 176), 256, 0, stream>>>(w2, w2_t, 2048, 5632);

    rmsnorm_cast<<<4096, 256, 0, stream>>>(x, wn1, C);
    gemm128<0><<<dim3(32, 48), 256, 0, stream>>>(C, wqkv_t, 6144, 2048,
                                                 nullptr, D, nullptr);
    rope_qk<<<4096, 256, 0, stream>>>(D, qT, kT);
    vtrans<<<dim3(32, 32, 2), 256, 0, stream>>>(D, vT);

    tcast<<<dim3(176, 64), 256, 0, stream>>>(w3, w3_t, 5632, 2048);

    attn_kernel<<<dim3(16, 32), 256, 0, stream>>>(qT, kT, vT, C);

    gemm128<1><<<dim3(32, 16), 256, 0, stream>>>(C, wproj_t, 2048, 2048,
                                                 x2, nullptr, x);
    rmsnorm_cast<<<4096, 256, 0, stream>>>(x2, wn2, C);
    gemm_ffn<<<dim3(32, 44), 256, 0, stream>>>(C, w1_t, w2_t, 5632, 2048, uu);
    gemm128<1><<<dim3(32, 16), 256, 0, stream>>>(uu, w3_t, 2048, 5632,
                                                 out, nullptr, x2);
}

// Round 5
// 849.685 us; speedup vs baseline: 1.3879x; 1.0463x over previous
//
#include <hip/hip_runtime.h>

typedef short s16x8 __attribute__((ext_vector_type(8)));
typedef unsigned short u16;
typedef u16 u16x8 __attribute__((ext_vector_type(8)));
typedef u16 u16x4 __attribute__((ext_vector_type(4)));
typedef float f32x4 __attribute__((ext_vector_type(4)));

#define DEVINL __device__ __forceinline__

DEVINL u16 f2bf(float f) {
    unsigned u = __float_as_uint(f);
    u += 0x7FFFu + ((u >> 16) & 1u);
    return (u16)(u >> 16);
}
DEVINL float bf2f(u16 h) { return __uint_as_float((unsigned)h << 16); }

DEVINL void gl2lds16(const void* g, void* l) {
    __builtin_amdgcn_global_load_lds((const __attribute__((address_space(1))) void*)g,
                                     (__attribute__((address_space(3))) void*)l, 16, 0, 0);
}

// ---------------------------------------------------------------------------
// Transpose-cast: src (K,N) fp32 row-major -> dst (N,K) bf16 row-major
// ---------------------------------------------------------------------------
__global__ __launch_bounds__(256) void tcast(
    const float* __restrict__ src, u16* __restrict__ dst, const int K, const int N)
{
    __shared__ float tile[32][33];
    const long k0 = (long)blockIdx.x * 32;
    const long n0 = (long)blockIdx.y * 32;
    const int tid = threadIdx.x;
    const int r = tid >> 3, c4 = (tid & 7) * 4;
    float4 v = *(const float4*)&src[(k0 + r) * N + n0 + c4];
    tile[r][c4] = v.x; tile[r][c4 + 1] = v.y; tile[r][c4 + 2] = v.z; tile[r][c4 + 3] = v.w;
    __syncthreads();
    u16x4 ov;
    ov[0] = f2bf(tile[c4][r]);     ov[1] = f2bf(tile[c4 + 1][r]);
    ov[2] = f2bf(tile[c4 + 2][r]); ov[3] = f2bf(tile[c4 + 3][r]);
    *(u16x4*)&dst[(n0 + r) * K + k0 + c4] = ov;
}

// ---------------------------------------------------------------------------
// RMSNorm (C=2048) fp32 -> bf16
// ---------------------------------------------------------------------------
__global__ __launch_bounds__(256) void rmsnorm_cast(
    const float* __restrict__ x, const float* __restrict__ wn, u16* __restrict__ out)
{
    const int C = 2048;
    const long row = blockIdx.x;
    const int tid = threadIdx.x;
    const float4* xr = (const float4*)(x + row * C);
    float4 a = xr[tid * 2], b = xr[tid * 2 + 1];
    float ss = a.x*a.x + a.y*a.y + a.z*a.z + a.w*a.w
             + b.x*b.x + b.y*b.y + b.z*b.z + b.w*b.w;
#pragma unroll
    for (int m = 1; m < 64; m <<= 1) ss += __shfl_xor(ss, m);
    __shared__ float red[4];
    if ((tid & 63) == 0) red[tid >> 6] = ss;
    __syncthreads();
    float scale = rsqrtf((red[0] + red[1] + red[2] + red[3]) * (1.f / 2048.f) + 1e-6f);
    const float4* wr = (const float4*)wn;
    float4 wa = wr[tid * 2], wb = wr[tid * 2 + 1];
    u16x8 o;
    o[0] = f2bf(a.x * scale * wa.x); o[1] = f2bf(a.y * scale * wa.y);
    o[2] = f2bf(a.z * scale * wa.z); o[3] = f2bf(a.w * scale * wa.w);
    o[4] = f2bf(b.x * scale * wb.x); o[5] = f2bf(b.y * scale * wb.y);
    o[6] = f2bf(b.z * scale * wb.z); o[7] = f2bf(b.w * scale * wb.w);
    *(u16x8*)&out[row * C + tid * 8] = o;
}

// ---------------------------------------------------------------------------
// GEMM: A (M x K) bf16 row-major, Bt (N x K) bf16 row-major, 128x128 tile.
// LDS tiles XOR-swizzled: chunk j of row r stored at slot j^(r&7).
// MODE 0: outB = bf16(acc)   MODE 1: outF = resid + acc (fp32)
// ---------------------------------------------------------------------------
template <int MODE>
__global__ __launch_bounds__(256, 2) void gemm128(
    const u16* __restrict__ A, const u16* __restrict__ Bt,
    const int N, const int K,
    float* __restrict__ outF, u16* __restrict__ outB,
    const float* __restrict__ resid)
{
    __shared__ u16 As[128 * 64];
    __shared__ u16 Bs[128 * 64];
    const int tid = threadIdx.x;
    const int lane = tid & 63;
    const int w = tid >> 6;
    const int wm = w >> 1, wn = w & 1;
    const int quad = lane >> 4, l16 = lane & 15;
    const long m0 = (long)blockIdx.x * 128;
    const long n0 = (long)blockIdx.y * 128;

    const u16* ga[4]; const u16* gb[4]; char* la[4]; char* lb[4];
#pragma unroll
    for (int rr = 0; rr < 4; ++rr) {
        int idx = rr * 256 + tid;
        int r = idx >> 3, j = idx & 7;
        int c = (j ^ (r & 7)) * 8;          // XOR source-swizzle
        ga[rr] = A + (m0 + r) * K + c;
        gb[rr] = Bt + (n0 + r) * K + c;
        la[rr] = (char*)As + idx * 16;
        lb[rr] = (char*)Bs + idx * 16;
    }

    f32x4 acc[4][4] = {};

    for (int k0 = 0; k0 < K; k0 += 64) {
#pragma unroll
        for (int rr = 0; rr < 4; ++rr) {
            gl2lds16(ga[rr] + k0, la[rr]);
            gl2lds16(gb[rr] + k0, lb[rr]);
        }
        __syncthreads();
#pragma unroll
        for (int ks = 0; ks < 2; ++ks) {
            s16x8 af[4], bfv[4];
#pragma unroll
            for (int mt = 0; mt < 4; ++mt)
                af[mt] = *(const s16x8*)&As[(wm * 64 + mt * 16 + l16) * 64 +
                                            ((ks * 4 + quad) ^ (l16 & 7)) * 8];
#pragma unroll
            for (int nt = 0; nt < 4; ++nt)
                bfv[nt] = *(const s16x8*)&Bs[(wn * 64 + nt * 16 + l16) * 64 +
                                             ((ks * 4 + quad) ^ (l16 & 7)) * 8];
#pragma unroll
            for (int mt = 0; mt < 4; ++mt)
#pragma unroll
                for (int nt = 0; nt < 4; ++nt)
                    acc[mt][nt] = __builtin_amdgcn_mfma_f32_16x16x32_bf16(af[mt], bfv[nt], acc[mt][nt], 0, 0, 0);
        }
        __syncthreads();
    }

#pragma unroll
    for (int mt = 0; mt < 4; ++mt)
#pragma unroll
        for (int reg = 0; reg < 4; ++reg) {
            long row = m0 + wm * 64 + mt * 16 + quad * 4 + reg;
#pragma unroll
            for (int nt = 0; nt < 4; ++nt) {
                long col = n0 + wn * 64 + nt * 16 + l16;
                float v = acc[mt][nt][reg];
                if (MODE == 0) {
                    outB[row * N + col] = f2bf(v);
                } else {
                    outF[row * N + col] = resid[row * N + col] + v;
                }
            }
        }
}

// ---------------------------------------------------------------------------
// Fused FFN up-projection: u = bf16( silu(A@B1t^T) * (A@B2t^T) )
// ---------------------------------------------------------------------------
__global__ __launch_bounds__(256, 2) void gemm_ffn(
    const u16* __restrict__ A, const u16* __restrict__ B1t, const u16* __restrict__ B2t,
    const int N, const int K, u16* __restrict__ outB)
{
    __shared__ u16 As[128 * 64];
    __shared__ u16 B1s[128 * 64];
    __shared__ u16 B2s[128 * 64];
    const int tid = threadIdx.x;
    const int lane = tid & 63;
    const int w = tid >> 6;
    const int wm = w >> 1, wn = w & 1;
    const int quad = lane >> 4, l16 = lane & 15;
    const long m0 = (long)blockIdx.x * 128;
    const long n0 = (long)blockIdx.y * 128;

    const u16* ga[4]; const u16* gb1[4]; const u16* gb2[4];
    char* la[4]; char* lb1[4]; char* lb2[4];
#pragma unroll
    for (int rr = 0; rr < 4; ++rr) {
        int idx = rr * 256 + tid;
        int r = idx >> 3, j = idx & 7;
        int c = (j ^ (r & 7)) * 8;
        ga[rr]  = A + (m0 + r) * K + c;
        gb1[rr] = B1t + (n0 + r) * K + c;
        gb2[rr] = B2t + (n0 + r) * K + c;
        la[rr]  = (char*)As + idx * 16;
        lb1[rr] = (char*)B1s + idx * 16;
        lb2[rr] = (char*)B2s + idx * 16;
    }

    f32x4 acc1[4][4] = {};
    f32x4 acc2[4][4] = {};

    for (int k0 = 0; k0 < K; k0 += 64) {
#pragma unroll
        for (int rr = 0; rr < 4; ++rr) {
            gl2lds16(ga[rr] + k0, la[rr]);
            gl2lds16(gb1[rr] + k0, lb1[rr]);
            gl2lds16(gb2[rr] + k0, lb2[rr]);
        }
        __syncthreads();
#pragma unroll
        for (int ks = 0; ks < 2; ++ks) {
            s16x8 af[4], b1f[4], b2f[4];
#pragma unroll
            for (int mt = 0; mt < 4; ++mt)
                af[mt] = *(const s16x8*)&As[(wm * 64 + mt * 16 + l16) * 64 +
                                            ((ks * 4 + quad) ^ (l16 & 7)) * 8];
#pragma unroll
            for (int nt = 0; nt < 4; ++nt) {
                b1f[nt] = *(const s16x8*)&B1s[(wn * 64 + nt * 16 + l16) * 64 +
                                              ((ks * 4 + quad) ^ (l16 & 7)) * 8];
                b2f[nt] = *(const s16x8*)&B2s[(wn * 64 + nt * 16 + l16) * 64 +
                                              ((ks * 4 + quad) ^ (l16 & 7)) * 8];
            }
#pragma unroll
            for (int mt = 0; mt < 4; ++mt)
#pragma unroll
                for (int nt = 0; nt < 4; ++nt) {
                    acc1[mt][nt] = __builtin_amdgcn_mfma_f32_16x16x32_bf16(af[mt], b1f[nt], acc1[mt][nt], 0, 0, 0);
                    acc2[mt][nt] = __builtin_amdgcn_mfma_f32_16x16x32_bf16(af[mt], b2f[nt], acc2[mt][nt], 0, 0, 0);
                }
        }
        __syncthreads();
    }

#pragma unroll
    for (int mt = 0; mt < 4; ++mt)
#pragma unroll
        for (int reg = 0; reg < 4; ++reg) {
            long row = m0 + wm * 64 + mt * 16 + quad * 4 + reg;
#pragma unroll
            for (int nt = 0; nt < 4; ++nt) {
                long col = n0 + wn * 64 + nt * 16 + l16;
                float g = acc1[mt][nt][reg];
                float s = g / (1.f + __expf(-g));
                outB[row * N + col] = f2bf(s * acc2[mt][nt][reg]);
            }
        }
}

// ---------------------------------------------------------------------------
// RoPE, vectorized: one block per (b,t) row; q scaled by 1/sqrt(D).
// qkv (B*T, 6144) bf16 -> qT/kT [bh][t][d]
// ---------------------------------------------------------------------------
__global__ __launch_bounds__(256) void rope_qk(
    const u16* __restrict__ qkv, u16* __restrict__ qT, u16* __restrict__ kT)
{
    const int row = blockIdx.x;
    const int t = row & 2047, b = row >> 11;
    const int tid = threadIdx.x;
    __shared__ u16 buf[4096];
    const u16* src = qkv + (long)row * 6144;
    u16x8 aa = *(const u16x8*)&src[tid * 8];
    u16x8 kk = *(const u16x8*)&src[2048 + tid * 8];
    *(u16x8*)&buf[tid * 8] = aa;
    *(u16x8*)&buf[2048 + tid * 8] = kk;
    __syncthreads();
    const int c = tid * 8;
    const int h = c >> 7, dh = c & 127;
    const bool first = dh < 64;
    const int pc = first ? (c + 64) : (c - 64);
    float cs[8], sn[8];
#pragma unroll
    for (int j = 0; j < 8; ++j) {
        float inv = __expf(-(float)((dh & 63) + j) * 0.14391156831212787f); // ln(1e4)/64
        float ang = (float)t * inv;
        cs[j] = cosf(ang); sn[j] = sinf(ang);
    }
    const long obase = ((long)(b * 16 + h) * 2048 + t) * 128 + dh;
#pragma unroll
    for (int part = 0; part < 2; ++part) {
        const int base = part * 2048;
        u16x8 mine = *(const u16x8*)&buf[base + c];
        u16x8 oth  = *(const u16x8*)&buf[base + pc];
        const float qs = part ? 1.f : 0.08838834764831845f;
        u16x8 o;
#pragma unroll
        for (int j = 0; j < 8; ++j) {
            float xv = bf2f(mine[j]), yv = bf2f(oth[j]);
            float ov = first ? (xv * cs[j] - yv * sn[j]) : (yv * sn[j] + xv * cs[j]);
            o[j] = f2bf(ov * qs);
        }
        u16* dst = part ? kT : qT;
        *(u16x8*)&dst[obase] = o;
    }
}

// ---------------------------------------------------------------------------
// v transpose: qkv v-part (b,t)(h,d) -> vT [bh][d][t].  LDS stride 65 (odd).
// ---------------------------------------------------------------------------
__global__ __launch_bounds__(256) void vtrans(
    const u16* __restrict__ qkv, u16* __restrict__ vT)
{
    const int bh = blockIdx.x;
    const int b = bh >> 4, h = bh & 15;
    const int t0 = blockIdx.y * 64, d0 = blockIdx.z * 64;
    __shared__ u16 tile[64 * 65];
    const int tid = threadIdx.x;
#pragma unroll
    for (int rr = 0; rr < 2; ++rr) {
        int idx = rr * 256 + tid;
        int r = idx >> 3, c = (idx & 7) * 8;
        u16x8 v = *(const u16x8*)&qkv[(long)(b * 2048 + t0 + r) * 6144 + 4096 + h * 128 + d0 + c];
#pragma unroll
        for (int j = 0; j < 8; ++j) tile[r * 65 + c + j] = v[j];
    }
    __syncthreads();
#pragma unroll
    for (int rr = 0; rr < 2; ++rr) {
        int idx = rr * 256 + tid;
        int dd = idx >> 3, cc = (idx & 7) * 8;
        u16x8 o;
#pragma unroll
        for (int j = 0; j < 8; ++j) o[j] = tile[(cc + j) * 65 + dd];
        *(u16x8*)&vT[((long)bh * 128 + d0 + dd) * 2048 + t0 + cc] = o;
    }
}

// ---------------------------------------------------------------------------
// Flash attention, causal. 1D grid 1024 blocks, 256 thr (4 waves, 16 q-rows
// each, QBLK=64). XCD-chunked swizzle: each XCD's contiguous chunk covers
// 4 bh (KV working set ~4 MB ~ its private L2), globally heavy-qt-first for
// causal load balance + backfill. Double-buffered K/V, XOR-swizzled LDS,
// q pre-scaled by 1/sqrt(D). T13 defer-max (skip o/li rescale while max
// growth <= 8) + T5 setprio around MFMA clusters.
// ---------------------------------------------------------------------------
__global__ __launch_bounds__(256, 2) void attn_kernel(
    const u16* __restrict__ qT, const u16* __restrict__ kT,
    const u16* __restrict__ vT, u16* __restrict__ outT)
{
    const int T = 2048, D = 128;
    // swizzle: lid -> (bh chunked per XCD, qt heavy-first)
    const int lid = blockIdx.x;
    const int swz = (lid & 7) * 128 + (lid >> 3);   // nwg=1024, chunk=128
    const int bh = swz >> 5;                        // 4 consecutive bh per XCD
    const int qt = 31 - (swz & 31);                 // heavy q-tiles first
    const int tid = threadIdx.x, lane = tid & 63, w = tid >> 6;
    const int quad = lane >> 4, l16 = lane & 15;
    const int qrow = qt * 64 + w * 16;

    __shared__ u16 Ks[2][64 * 128];
    __shared__ u16 Vs[2][128 * 64];
    __shared__ u16 Ps[4][16 * 64];

    s16x8 aq[4];
    const u16* qb = qT + ((long)bh * T + qrow + l16) * D;
#pragma unroll
    for (int kk = 0; kk < 4; ++kk)
        aq[kk] = *(const s16x8*)&qb[kk * 32 + quad * 8];

    f32x4 o[8] = {};
    float mi[4] = {-INFINITY, -INFINITY, -INFINITY, -INFINITY};
    float li[4] = {0.f, 0.f, 0.f, 0.f};

    const u16* kg0 = kT + (long)bh * T * D;
    const u16* vg0 = vT + (long)bh * D * T;

    auto stage = [&](int kt, int b) {
        const int k0 = kt * 64;
#pragma unroll
        for (int rr = 0; rr < 4; ++rr) {
            int idx = rr * 256 + tid;
            int kr = idx >> 4, kj = idx & 15;
            gl2lds16(kg0 + (long)(k0 + kr) * D + ((kj ^ (kr & 15)) * 8),
                     (char*)Ks[b] + idx * 16);
            int vr = idx >> 3, vj = idx & 7;
            gl2lds16(vg0 + (long)vr * T + k0 + ((vj ^ (vr & 7)) * 8),
                     (char*)Vs[b] + idx * 16);
        }
    };

    stage(0, 0);

    for (int kt = 0; kt <= qt; ++kt) {
        __syncthreads();                 // buf[kt&1] ready (loads had 1 full iter)
        if (kt < qt) stage(kt + 1, (kt + 1) & 1);
        const u16* ks_ = Ks[kt & 1];
        const u16* vs_ = Vs[kt & 1];
        const int k0 = kt * 64;

        // S = Q K^T
        f32x4 sf[4] = {};
        __builtin_amdgcn_s_setprio(1);
#pragma unroll
        for (int kk = 0; kk < 4; ++kk) {
#pragma unroll
            for (int nt = 0; nt < 4; ++nt) {
                s16x8 kb = *(const s16x8*)&ks_[(nt * 16 + l16) * 128 +
                                               ((kk * 4 + quad) ^ (l16 & 15)) * 8];
                sf[nt] = __builtin_amdgcn_mfma_f32_16x16x32_bf16(aq[kk], kb, sf[nt], 0, 0, 0);
            }
        }
        __builtin_amdgcn_s_setprio(0);

        float S[4][4];
        if (kt == qt) {   // diagonal tile: causal mask
#pragma unroll
            for (int nt = 0; nt < 4; ++nt) {
                int col = k0 + nt * 16 + l16;
#pragma unroll
                for (int reg = 0; reg < 4; ++reg) {
                    int row = qrow + quad * 4 + reg;
                    S[nt][reg] = (col <= row) ? sf[nt][reg] : -INFINITY;
                }
            }
        } else {
#pragma unroll
            for (int nt = 0; nt < 4; ++nt)
#pragma unroll
                for (int reg = 0; reg < 4; ++reg)
                    S[nt][reg] = sf[nt][reg];
        }

        float rm[4];
#pragma unroll
        for (int reg = 0; reg < 4; ++reg)
            rm[reg] = fmaxf(fmaxf(S[0][reg], S[1][reg]), fmaxf(S[2][reg], S[3][reg]));
#pragma unroll
        for (int m = 1; m < 16; m <<= 1)
#pragma unroll
            for (int reg = 0; reg < 4; ++reg)
                rm[reg] = fmaxf(rm[reg], __shfl_xor(rm[reg], m));

        // T13 defer-max: only rescale when the running max grew by > 8
        int cond = 1;
#pragma unroll
        for (int reg = 0; reg < 4; ++reg)
            cond &= (rm[reg] - mi[reg] <= 8.f) ? 1 : 0;
        if (!__all(cond)) {
            float alpha[4];
#pragma unroll
            for (int reg = 0; reg < 4; ++reg) {
                float mn = fmaxf(mi[reg], rm[reg]);
                alpha[reg] = __expf(mi[reg] - mn);
                mi[reg] = mn;
                li[reg] *= alpha[reg];
            }
#pragma unroll
            for (int dt = 0; dt < 8; ++dt)
#pragma unroll
                for (int reg = 0; reg < 4; ++reg)
                    o[dt][reg] *= alpha[reg];
        }

        float rs[4] = {};
#pragma unroll
        for (int nt = 0; nt < 4; ++nt)
#pragma unroll
            for (int reg = 0; reg < 4; ++reg) {
                float p = __expf(S[nt][reg] - mi[reg]);
                S[nt][reg] = p;
                rs[reg] += p;
            }
#pragma unroll
        for (int m = 1; m < 16; m <<= 1)
#pragma unroll
            for (int reg = 0; reg < 4; ++reg)
                rs[reg] += __shfl_xor(rs[reg], m);
#pragma unroll
        for (int reg = 0; reg < 4; ++reg)
            li[reg] += rs[reg];

        // P -> LDS, wave-private region (no barrier needed), XOR-swizzled
#pragma unroll
        for (int nt = 0; nt < 4; ++nt)
#pragma unroll
            for (int reg = 0; reg < 4; ++reg) {
                int prow = quad * 4 + reg;
                int pcol = nt * 16 + l16;
                Ps[w][prow * 64 + (((pcol >> 3) ^ (prow & 7)) * 8) + (pcol & 7)]
                    = f2bf(S[nt][reg]);
            }

        // O += P V   (Ps read: row l16, chunk ks*4+quad, swizzled)
        __builtin_amdgcn_s_setprio(1);
#pragma unroll
        for (int ks = 0; ks < 2; ++ks) {
            s16x8 pa = *(const s16x8*)&Ps[w][l16 * 64 +
                                             ((ks * 4 + quad) ^ (l16 & 7)) * 8];
#pragma unroll
            for (int dt = 0; dt < 8; ++dt) {
                s16x8 vb = *(const s16x8*)&vs_[(dt * 16 + l16) * 64 +
                                               ((ks * 4 + quad) ^ (l16 & 7)) * 8];
                o[dt] = __builtin_amdgcn_mfma_f32_16x16x32_bf16(pa, vb, o[dt], 0, 0, 0);
            }
        }
        __builtin_amdgcn_s_setprio(0);
    }

    const int b = bh >> 4, h = bh & 15;
#pragma unroll
    for (int reg = 0; reg < 4; ++reg) {
        float inv = 1.f / li[reg];
        int t = qrow + quad * 4 + reg;
        u16* orow = outT + ((long)(b * T + t)) * 2048 + h * 128;
#pragma unroll
        for (int dt = 0; dt < 8; ++dt)
            orow[dt * 16 + l16] = f2bf(o[dt][reg] * inv);
    }
}

// ---------------------------------------------------------------------------
// Workspace layout (188 MiB total, unions by live-range):
//   Z 24 MiB: wqkv_t -> w3_t | wproj 8 | w1_t 22 | w2_t 22
//   C 16 MiB: h -> attn_out -> h2 | D 48 MiB: qkv -> u | E 48 MiB: q/k/vT -> x2
// ---------------------------------------------------------------------------
extern "C" void kernel_launch(void* const* d_in, const int* in_sizes, int n_in,
                              void* d_out, int out_size, void* d_ws, size_t ws_size,
                              hipStream_t stream) {
    const float* x      = (const float*)d_in[0];
    const float* wn1    = (const float*)d_in[1];
    const float* w_qkv  = (const float*)d_in[2];
    const float* w_proj = (const float*)d_in[3];
    const float* wn2    = (const float*)d_in[4];
    const float* w1     = (const float*)d_in[5];
    const float* w2     = (const float*)d_in[6];
    const float* w3     = (const float*)d_in[7];
    float* out = (float*)d_out;

    char* p = (char*)d_ws;
    u16* Z       = (u16*)p; p += (size_t)6144 * 2048 * 2;
    u16* wproj_t = (u16*)p; p += (size_t)2048 * 2048 * 2;
    u16* w1_t    = (u16*)p; p += (size_t)5632 * 2048 * 2;
    u16* w2_t    = (u16*)p; p += (size_t)5632 * 2048 * 2;
    u16* C       = (u16*)p; p += (size_t)4096 * 2048 * 2;
    u16* D       = (u16*)p; p += (size_t)4096 * 6144 * 2;
    u16* E       = (u16*)p; p += (size_t)3 * 32 * 2048 * 128 * 2;

    u16* wqkv_t = Z;
    u16* w3_t   = Z;
    u16* qT = E;
    u16* kT = E + (size_t)32 * 2048 * 128;
    u16* vT = E + (size_t)2 * 32 * 2048 * 128;
    float* x2 = (float*)E;
    u16* uu = D;

    tcast<<<dim3(64, 192), 256, 0, stream>>>(w_qkv, wqkv_t, 2048, 6144);
    tcast<<<dim3(64, 64), 256, 0, stream>>>(w_proj, wproj_t, 2048, 2048);
    tcast<<<dim3(64, 176), 256, 0, stream>>>(w1, w1_t, 2048, 5632);
    tcast<<<dim3(64, 176), 256, 0, stream>>>(w2, w2_t, 2048, 5632);

    rmsnorm_cast<<<4096, 256, 0, stream>>>(x, wn1, C);
    gemm128<0><<<dim3(32, 48), 256, 0, stream>>>(C, wqkv_t, 6144, 2048,
                                                 nullptr, D, nullptr);
    rope_qk<<<4096, 256, 0, stream>>>(D, qT, kT);
    vtrans<<<dim3(32, 32, 2), 256, 0, stream>>>(D, vT);

    tcast<<<dim3(176, 64), 256, 0, stream>>>(w3, w3_t, 5632, 2048);

    attn_kernel<<<1024, 256, 0, stream>>>(qT, kT, vT, C);

    gemm128<1><<<dim3(32, 16), 256, 0, stream>>>(C, wproj_t, 2048, 2048,
                                                 x2, nullptr, x);
    rmsnorm_cast<<<4096, 256, 0, stream>>>(x2, wn2, C);
    gemm_ffn<<<dim3(32, 44), 256, 0, stream>>>(C, w1_t, w2_t, 5632, 2048, uu);
    gemm128<1><<<dim3(32, 16), 256, 0, stream>>>(uu, w3_t, 2048, 5632,
                                                 out, nullptr, x2);
}